// Round 1
// baseline (1019.361 us; speedup 1.0000x reference)
//
#include <hip/hip_runtime.h>
#include <hip/hip_bf16.h>
#include <math.h>

#define NN   50000
#define NE   1600000
#define EP   (NE + NN)       // edges + self loops = 1,650,000
#define INC  64
#define HIDC 16
#define NH   8
#define C1   128             // NH*HIDC
#define OUTC 32
#define NB   256

__device__ __forceinline__ float elu_f(float x)   { return x > 0.0f ? x : expm1f(x); }
__device__ __forceinline__ float lrelu_f(float x) { return x > 0.0f ? x : 0.2f * x; }

// ---------------- GEMM1: xl1 = x@wl1+bl1, xr1 = x@wr1+br1  ([N,64]x[64,128]) ----
__global__ __launch_bounds__(256) void k_gemm1(
    const float* __restrict__ x, const float* __restrict__ wl,
    const float* __restrict__ bl, const float* __restrict__ wr,
    const float* __restrict__ br, float* __restrict__ xl1, float* __restrict__ xr1)
{
    __shared__ float xs[32 * 64];
    const int tid = threadIdx.x;
    const int n0  = blockIdx.x * 32;
    int nrem = NN - n0; if (nrem > 32) nrem = 32;

    // x rows are contiguous: load 32 rows (2048 floats) as float4
    const float4* xg = (const float4*)(x + (size_t)n0 * 64);
    float4* xs4 = (float4*)xs;
    const int lim4 = (nrem * 64) >> 2;
    for (int i = tid; i < lim4; i += 256) xs4[i] = xg[i];
    __syncthreads();

    const int col = tid & 127;
    const float* w   = (tid < 128) ? wl : wr;
    const float bias = (tid < 128) ? bl[col] : br[col];
    float* outp      = (tid < 128) ? xl1 : xr1;

    float acc[32];
#pragma unroll
    for (int n = 0; n < 32; ++n) acc[n] = 0.0f;

    for (int k4 = 0; k4 < 16; ++k4) {
        const float w0 = w[(k4*4+0)*128 + col];
        const float w1 = w[(k4*4+1)*128 + col];
        const float w2 = w[(k4*4+2)*128 + col];
        const float w3 = w[(k4*4+3)*128 + col];
#pragma unroll
        for (int n = 0; n < 32; ++n) {
            float4 xv = xs4[n*16 + k4];   // LDS broadcast
            acc[n] += xv.x*w0 + xv.y*w1 + xv.z*w2 + xv.w*w3;
        }
    }
    for (int n = 0; n < nrem; ++n)
        outp[(size_t)(n0+n)*128 + col] = acc[n] + bias;
}

// ---------------- CSR build ----------------------------------------------------
__global__ void k_count(const int* __restrict__ ei, int* __restrict__ counts)
{
    int e = blockIdx.x * 256 + threadIdx.x;
    if (e >= EP) return;
    int d = (e < NE) ? ei[NE + e] : (e - NE);
    atomicAdd(&counts[d], 1);
}

__global__ __launch_bounds__(1024) void k_scan(const int* __restrict__ counts,
                                               int* __restrict__ rowp,
                                               int* __restrict__ cursor)
{
    __shared__ int part[1024];
    const int tid = threadIdx.x;
    const int CH  = (NN + 1023) / 1024;   // 49
    const int base = tid * CH;
    int s = 0;
    for (int i = 0; i < CH; ++i) {
        int idx = base + i;
        if (idx < NN) s += counts[idx];
    }
    part[tid] = s;
    __syncthreads();
    for (int ofs = 1; ofs < 1024; ofs <<= 1) {
        int v = (tid >= ofs) ? part[tid - ofs] : 0;
        __syncthreads();
        part[tid] += v;
        __syncthreads();
    }
    int run = (tid == 0) ? 0 : part[tid - 1];
    for (int i = 0; i < CH; ++i) {
        int idx = base + i;
        if (idx < NN) {
            rowp[idx] = run; cursor[idx] = run;
            run += counts[idx];
        }
    }
    if (tid == 0) rowp[NN] = EP;
}

__global__ void k_fill(const int* __restrict__ ei, int* __restrict__ cursor,
                       int* __restrict__ elist)
{
    int e = blockIdx.x * 256 + threadIdx.x;
    if (e >= EP) return;
    int d = (e < NE) ? ei[NE + e] : (e - NE);
    int pos = atomicAdd(&cursor[d], 1);
    elist[pos] = e;
}

// ---------------- conv1 aggregation: one wave per dst, online softmax ----------
__global__ __launch_bounds__(256) void k_conv1_agg(
    const float* __restrict__ xl1, const float* __restrict__ xr1,
    const float* __restrict__ att, const float* __restrict__ bias1,
    const int* __restrict__ rowp, const int* __restrict__ elist,
    const int* __restrict__ ei, float* __restrict__ h1)
{
    const int d = (blockIdx.x * 256 + threadIdx.x) >> 6;   // dst node = global wave id
    if (d >= NN) return;
    const int lane = threadIdx.x & 63;
    const int h = lane >> 3, j = lane & 7;
    const int c0 = h * 16 + 2 * j;                         // this lane's channel pair

    const float2 xr = *(const float2*)&xr1[(size_t)d * 128 + c0];
    const float2 at = *(const float2*)&att[h * 16 + 2 * j];
    const int beg = rowp[d], end = rowp[d + 1];

    float m = -__builtin_inff(), den = 0.f, a0 = 0.f, a1 = 0.f;
    for (int e = beg; e < end; ++e) {
        int eid = elist[e];
        int s = (eid < NE) ? ei[eid] : (eid - NE);
        float2 v = *(const float2*)&xl1[(size_t)s * 128 + c0];
        float t0 = lrelu_f(v.x + xr.x);
        float t1 = lrelu_f(v.y + xr.y);
        float p = at.x * t0 + at.y * t1;
        p += __shfl_xor(p, 1);     // reduce over the 8 lanes of this head
        p += __shfl_xor(p, 2);
        p += __shfl_xor(p, 4);
        float nm   = fmaxf(m, p);
        float corr = __expf(m - nm);   // 0 on first iter (m = -inf)
        float w    = __expf(p - nm);
        den = den * corr + w;
        a0  = a0  * corr + w * v.x;
        a1  = a1  * corr + w * v.y;
        m = nm;
    }
    const float inv = 1.0f / (den + 1e-16f);
    float o0 = elu_f(a0 * inv + bias1[c0]);
    float o1 = elu_f(a1 * inv + bias1[c0 + 1]);
    *(float2*)&h1[(size_t)d * 128 + c0] = make_float2(o0, o1);
}

// ---------------- GEMM2: xl2 = h1@wl2+bl2, xr2 = h1@wr2+br2 ([N,128]x[128,16]) -
__global__ __launch_bounds__(256) void k_gemm2(
    const float* __restrict__ h1, const float* __restrict__ wl,
    const float* __restrict__ bl, const float* __restrict__ wr,
    const float* __restrict__ br, float* __restrict__ xl2, float* __restrict__ xr2)
{
    __shared__ float xs[8 * 128];
    const int tid = threadIdx.x;
    const int n0  = blockIdx.x * 8;      // N % 8 == 0 -> no tail
    const float4* xg = (const float4*)(h1 + (size_t)n0 * 128);
    float4* xs4 = (float4*)xs;
    xs4[tid] = xg[tid];                  // 256 float4 = 8 rows
    __syncthreads();

    const int nl  = tid >> 5;
    const int col = tid & 31;
    const int c   = col & 15;
    const float* w   = (col < 16) ? wl : wr;
    const float bias = (col < 16) ? bl[c] : br[c];
    float* outp      = (col < 16) ? xl2 : xr2;

    float acc = 0.f;
    for (int k4 = 0; k4 < 32; ++k4) {
        float4 xv = xs4[nl * 32 + k4];
        acc += xv.x * w[(k4*4+0)*16 + c] + xv.y * w[(k4*4+1)*16 + c]
             + xv.z * w[(k4*4+2)*16 + c] + xv.w * w[(k4*4+3)*16 + c];
    }
    outp[(size_t)(n0 + nl) * 16 + c] = acc + bias;
}

// ---------------- conv2 aggregation: 16 lanes per dst --------------------------
__global__ __launch_bounds__(256) void k_conv2_agg(
    const float* __restrict__ xl2, const float* __restrict__ xr2,
    const float* __restrict__ att, const float* __restrict__ bias2,
    const int* __restrict__ rowp, const int* __restrict__ elist,
    const int* __restrict__ ei, float* __restrict__ h2)
{
    const int d = (blockIdx.x * 256 + threadIdx.x) >> 4;
    if (d >= NN) return;
    const int c = threadIdx.x & 15;
    const float xr = xr2[(size_t)d * 16 + c];
    const float at = att[c];
    const int beg = rowp[d], end = rowp[d + 1];

    float m = -__builtin_inff(), den = 0.f, acc = 0.f;
    for (int e = beg; e < end; ++e) {
        int eid = elist[e];
        int s = (eid < NE) ? ei[eid] : (eid - NE);
        float v = xl2[(size_t)s * 16 + c];
        float p = at * lrelu_f(v + xr);
        p += __shfl_xor(p, 1);
        p += __shfl_xor(p, 2);
        p += __shfl_xor(p, 4);
        p += __shfl_xor(p, 8);
        float nm   = fmaxf(m, p);
        float corr = __expf(m - nm);
        float w    = __expf(p - nm);
        den = den * corr + w;
        acc = acc * corr + w * v;
        m = nm;
    }
    float o = acc / (den + 1e-16f) + bias2[c];
    h2[(size_t)d * 16 + c] = elu_f(o);
}

// ---------------- global mean pool (atomics) -----------------------------------
__global__ void k_pool(const float* __restrict__ h2, const int* __restrict__ batch,
                       float* __restrict__ pooled, float* __restrict__ cnt)
{
    int i = blockIdx.x * 256 + threadIdx.x;
    if (i >= NN * 16) return;
    int n = i >> 4, c = i & 15;
    int b = batch[n];
    atomicAdd(&pooled[b * 16 + c], h2[i]);
    if (c == 0) atomicAdd(&cnt[b], 1.0f);
}

// ---------------- MLP head: one thread per graph -------------------------------
__global__ __launch_bounds__(256) void k_mlp(
    const float* __restrict__ pooled, const float* __restrict__ cnt,
    const float* __restrict__ w1, const float* __restrict__ b1,
    const float* __restrict__ w2, const float* __restrict__ b2,
    const float* __restrict__ w3, const float* __restrict__ b3,
    float* __restrict__ out)
{
    __shared__ float w1s[16*32], w2s[32*16], w3s[16*32], b1s[32], b2s[16], b3s[32];
    const int tid = threadIdx.x;
    for (int i = tid; i < 512; i += 256) { w1s[i] = w1[i]; w2s[i] = w2[i]; w3s[i] = w3[i]; }
    if (tid < 32) b1s[tid] = b1[tid];
    if (tid < 16) b2s[tid] = b2[tid];
    if (tid < 32) b3s[tid] = b3[tid];
    __syncthreads();

    const int g = tid;  // graph id, 0..255
    const float inv = 1.0f / fmaxf(cnt[g], 1.0f);
    float hb[16];
#pragma unroll
    for (int k = 0; k < 16; ++k) hb[k] = pooled[g * 16 + k] * inv;

    float t1[32];
#pragma unroll
    for (int j = 0; j < 32; ++j) t1[j] = b1s[j];
    for (int k = 0; k < 16; ++k)
#pragma unroll
        for (int j = 0; j < 32; ++j) t1[j] += hb[k] * w1s[k * 32 + j];
#pragma unroll
    for (int j = 0; j < 32; ++j) t1[j] = elu_f(t1[j]);

    float t2[16];
#pragma unroll
    for (int j = 0; j < 16; ++j) t2[j] = b2s[j];
    for (int k = 0; k < 32; ++k)
#pragma unroll
        for (int j = 0; j < 16; ++j) t2[j] += t1[k] * w2s[k * 16 + j];
#pragma unroll
    for (int j = 0; j < 16; ++j) t2[j] = elu_f(t2[j]);

#pragma unroll
    for (int j = 0; j < 32; ++j) {
        float o = b3s[j];
        for (int k = 0; k < 16; ++k) o += t2[k] * w3s[k * 32 + j];
        out[g * 32 + j] = o;
    }
}

// ---------------- launch -------------------------------------------------------
extern "C" void kernel_launch(void* const* d_in, const int* in_sizes, int n_in,
                              void* d_out, int out_size, void* d_ws, size_t ws_size,
                              hipStream_t stream)
{
    const float* x     = (const float*)d_in[0];
    const int*   ei    = (const int*)d_in[1];
    const int*   batch = (const int*)d_in[2];
    const float* wl1   = (const float*)d_in[3];
    const float* bl1   = (const float*)d_in[4];
    const float* wr1   = (const float*)d_in[5];
    const float* br1   = (const float*)d_in[6];
    const float* att1  = (const float*)d_in[7];
    const float* bias1 = (const float*)d_in[8];
    const float* wl2   = (const float*)d_in[9];
    const float* bl2   = (const float*)d_in[10];
    const float* wr2   = (const float*)d_in[11];
    const float* br2   = (const float*)d_in[12];
    const float* att2  = (const float*)d_in[13];
    const float* bias2 = (const float*)d_in[14];
    const float* wm1   = (const float*)d_in[15];
    const float* bm1   = (const float*)d_in[16];
    const float* wm2   = (const float*)d_in[17];
    const float* bm2   = (const float*)d_in[18];
    const float* wm3   = (const float*)d_in[19];
    const float* bm3   = (const float*)d_in[20];
    float* out = (float*)d_out;

    char* base = (char*)d_ws;
    size_t off = 0;
    auto alloc = [&](size_t bytes) -> void* {
        void* p = base + off;
        off += (bytes + 255) & ~(size_t)255;
        return p;
    };
    float* xl1  = (float*)alloc((size_t)NN * 128 * 4);
    float* xr1  = (float*)alloc((size_t)NN * 128 * 4);
    float* h1   = (float*)alloc((size_t)NN * 128 * 4);
    int*   elist= (int*)  alloc((size_t)EP * 4);
    int*   rowp = (int*)  alloc((size_t)(NN + 1) * 4);
    int*   cursor=(int*)  alloc((size_t)NN * 4);
    char*  zbase = base + off;                 // contiguous zero region start
    int*   counts=(int*)  alloc((size_t)NN * 4);
    float* pooled=(float*)alloc((size_t)NB * 16 * 4);
    float* cnt  = (float*)alloc((size_t)NB * 4);
    size_t zbytes = (size_t)((base + off) - zbase);
    // conv2 tensors reuse xl1's region (free after k_conv1_agg)
    float* xl2 = xl1;
    float* xr2 = xl1 + (size_t)NN * 16;
    float* h2  = xl1 + (size_t)NN * 32;

    hipMemsetAsync(zbase, 0, zbytes, stream);
    k_gemm1<<<(NN + 31) / 32, 256, 0, stream>>>(x, wl1, bl1, wr1, br1, xl1, xr1);
    k_count<<<(EP + 255) / 256, 256, 0, stream>>>(ei, counts);
    k_scan<<<1, 1024, 0, stream>>>(counts, rowp, cursor);
    k_fill<<<(EP + 255) / 256, 256, 0, stream>>>(ei, cursor, elist);
    k_conv1_agg<<<(NN * 64) / 256, 256, 0, stream>>>(xl1, xr1, att1, bias1, rowp, elist, ei, h1);
    k_gemm2<<<NN / 8, 256, 0, stream>>>(h1, wl2, bl2, wr2, br2, xl2, xr2);
    k_conv2_agg<<<(NN * 16) / 256, 256, 0, stream>>>(xl2, xr2, att2, bias2, rowp, elist, ei, h2);
    k_pool<<<(NN * 16 + 255) / 256, 256, 0, stream>>>(h2, batch, pooled, cnt);
    k_mlp<<<1, 256, 0, stream>>>(pooled, cnt, wm1, bm1, wm2, bm2, wm3, bm3, out);
}

// Round 3
// 782.231 us; speedup vs baseline: 1.3031x; 1.3031x over previous
//
#include <hip/hip_runtime.h>
#include <hip/hip_bf16.h>
#include <math.h>

#define NN   50000
#define NE   1600000
#define EP   (NE + NN)       // edges + self loops = 1,650,000
#define NB   256

#define NEG_INF (-__builtin_inff())

__device__ __forceinline__ float elu_f(float x)   { return x > 0.0f ? x : expm1f(x); }
__device__ __forceinline__ float lrelu_f(float x) { return x > 0.0f ? x : 0.2f * x; }

// ---------------- GEMM1: xl1 = x@wl1+bl1, xr1 = x@wr1+br1  ([N,64]x[64,128]) ----
__global__ __launch_bounds__(256) void k_gemm1(
    const float* __restrict__ x, const float* __restrict__ wl,
    const float* __restrict__ bl, const float* __restrict__ wr,
    const float* __restrict__ br, float* __restrict__ xl1, float* __restrict__ xr1)
{
    __shared__ float xs[32 * 64];
    const int tid = threadIdx.x;
    const int n0  = blockIdx.x * 32;
    const int nrem = min(32, NN - n0);

    const float4* xg = (const float4*)(x + (size_t)n0 * 64);
    float4* xs4 = (float4*)xs;
    const int lim4 = nrem * 16;
    for (int i = tid; i < lim4; i += 256) xs4[i] = xg[i];
    __syncthreads();

    const int g  = tid >> 6;        // 0..3 -> rows 8g..8g+7
    const int c0 = (tid & 63) * 4;  // 0..252
    const float* w; const float* b; float* outp; int cw;
    if (c0 < 128) { w = wl; b = bl; outp = xl1; cw = c0; }
    else          { w = wr; b = br; outp = xr1; cw = c0 - 128; }

    float4 acc[8];
#pragma unroll
    for (int r = 0; r < 8; ++r) acc[r] = make_float4(0.f, 0.f, 0.f, 0.f);

    for (int k4 = 0; k4 < 16; ++k4) {
        const float4 w0 = *(const float4*)&w[(k4*4+0)*128 + cw];
        const float4 w1 = *(const float4*)&w[(k4*4+1)*128 + cw];
        const float4 w2 = *(const float4*)&w[(k4*4+2)*128 + cw];
        const float4 w3 = *(const float4*)&w[(k4*4+3)*128 + cw];
#pragma unroll
        for (int r = 0; r < 8; ++r) {
            const float4 xv = xs4[(g*8+r)*16 + k4];
            acc[r].x += xv.x*w0.x + xv.y*w1.x + xv.z*w2.x + xv.w*w3.x;
            acc[r].y += xv.x*w0.y + xv.y*w1.y + xv.z*w2.y + xv.w*w3.y;
            acc[r].z += xv.x*w0.z + xv.y*w1.z + xv.z*w2.z + xv.w*w3.z;
            acc[r].w += xv.x*w0.w + xv.y*w1.w + xv.z*w2.w + xv.w*w3.w;
        }
    }
    const float4 bv = *(const float4*)&b[cw];
#pragma unroll
    for (int r = 0; r < 8; ++r) {
        const int row = g*8 + r;
        if (row < nrem) {
            float4 o = make_float4(acc[r].x + bv.x, acc[r].y + bv.y,
                                   acc[r].z + bv.z, acc[r].w + bv.w);
            *(float4*)&outp[(size_t)(n0 + row) * 128 + cw] = o;
        }
    }
}

// ---------------- CSR build ----------------------------------------------------
__global__ void k_count(const int* __restrict__ ei, int* __restrict__ counts)
{
    int e = blockIdx.x * 256 + threadIdx.x;
    if (e >= EP) return;
    int d = (e < NE) ? ei[NE + e] : (e - NE);
    atomicAdd(&counts[d], 1);
}

__global__ __launch_bounds__(1024) void k_scan(const int* __restrict__ counts,
                                               int* __restrict__ rowp,
                                               int* __restrict__ cursor)
{
    __shared__ int part[1024];
    const int tid = threadIdx.x;
    const int CH  = (NN + 1023) / 1024;   // 49
    const int base = tid * CH;
    int s = 0;
    for (int i = 0; i < CH; ++i) {
        int idx = base + i;
        if (idx < NN) s += counts[idx];
    }
    part[tid] = s;
    __syncthreads();
    for (int ofs = 1; ofs < 1024; ofs <<= 1) {
        int v = (tid >= ofs) ? part[tid - ofs] : 0;
        __syncthreads();
        part[tid] += v;
        __syncthreads();
    }
    int run = (tid == 0) ? 0 : part[tid - 1];
    for (int i = 0; i < CH; ++i) {
        int idx = base + i;
        if (idx < NN) {
            rowp[idx] = run; cursor[idx] = run;
            run += counts[idx];
        }
    }
    if (tid == 0) rowp[NN] = EP;
}

// slist[pos] = SOURCE node of the edge (dst-sorted)
__global__ void k_fill(const int* __restrict__ ei, int* __restrict__ cursor,
                       int* __restrict__ slist)
{
    int e = blockIdx.x * 256 + threadIdx.x;
    if (e >= EP) return;
    int s, d;
    if (e < NE) { s = ei[e]; d = ei[NE + e]; }
    else        { s = e - NE; d = s; }
    int pos = atomicAdd(&cursor[d], 1);
    slist[pos] = s;
}

// ---------------- conv1 aggregation: one wave per dst, online softmax ----------
// Batched src-id loads + depth-3 prefetch; edge order and update sequence are
// bitwise identical to the R1 version that passed.
__global__ __launch_bounds__(256) void k_conv1_agg(
    const float* __restrict__ xl1, const float* __restrict__ xr1,
    const float* __restrict__ att, const float* __restrict__ bias1,
    const int* __restrict__ rowp, const int* __restrict__ slist,
    float* __restrict__ h1)
{
    const int d = (blockIdx.x * 256 + threadIdx.x) >> 6;
    if (d >= NN) return;
    const int lane = threadIdx.x & 63;
    const int c0 = 2 * lane;                 // head = lane>>3, channels c0..c0+1

    const float2 xr = *(const float2*)&xr1[(size_t)d * 128 + c0];
    const float2 at = *(const float2*)&att[c0];
    const int beg = rowp[d], end = rowp[d + 1];

    float m = NEG_INF, den = 0.f, a0 = 0.f, a1 = 0.f;

    for (int base = beg; base < end; base += 64) {
        const int n = min(64, end - base);
        int sv = (lane < n) ? slist[base + lane] : 0;
        float2 v0, v1, v2;
        { int s = __shfl(sv, 0); v0 = *(const float2*)&xl1[(size_t)s*128 + c0]; }
        v1 = v0; v2 = v0;
        if (n > 1) { int s = __shfl(sv, 1); v1 = *(const float2*)&xl1[(size_t)s*128 + c0]; }
        if (n > 2) { int s = __shfl(sv, 2); v2 = *(const float2*)&xl1[(size_t)s*128 + c0]; }
        for (int i = 0; i < n; ++i) {
            float2 vn = v0;
            if (i + 3 < n) { int s = __shfl(sv, i + 3);
                             vn = *(const float2*)&xl1[(size_t)s*128 + c0]; }
            float t0 = lrelu_f(v0.x + xr.x);
            float t1 = lrelu_f(v0.y + xr.y);
            float p = at.x * t0 + at.y * t1;
            p += __shfl_xor(p, 1);           // reduce over the 8 lanes of this head
            p += __shfl_xor(p, 2);
            p += __shfl_xor(p, 4);
            float nm   = fmaxf(m, p);
            float corr = __expf(m - nm);
            float w    = __expf(p - nm);
            den = den * corr + w;
            a0  = a0  * corr + w * v0.x;
            a1  = a1  * corr + w * v0.y;
            m = nm;
            v0 = v1; v1 = v2; v2 = vn;
        }
    }
    const float inv = 1.0f / (den + 1e-16f);
    float o0 = elu_f(a0 * inv + bias1[c0]);
    float o1 = elu_f(a1 * inv + bias1[c0 + 1]);
    *(float2*)&h1[(size_t)d * 128 + c0] = make_float2(o0, o1);
}

// ---------------- GEMM2: xl2 = h1@wl2+bl2, xr2 = h1@wr2+br2 ([N,128]x[128,16]) -
__global__ __launch_bounds__(256) void k_gemm2(
    const float* __restrict__ h1, const float* __restrict__ wl,
    const float* __restrict__ bl, const float* __restrict__ wr,
    const float* __restrict__ br, float* __restrict__ xl2, float* __restrict__ xr2)
{
    __shared__ float xs[32 * 132];
    const int tid = threadIdx.x;
    const int n0  = blockIdx.x * 32;
    const int nrem = min(32, NN - n0);

    for (int i = tid; i < nrem * 128; i += 256) {
        int row = i >> 7, col = i & 127;
        xs[row * 132 + col] = h1[(size_t)(n0 + row) * 128 + col];
    }
    __syncthreads();

    const int r  = tid >> 3;        // 0..31
    const int c0 = (tid & 7) * 4;   // 0..28
    const float* w; const float* b; float* outp; int c;
    if (c0 < 16) { w = wl; b = bl; outp = xl2; c = c0; }
    else         { w = wr; b = br; outp = xr2; c = c0 - 16; }

    float4 acc = make_float4(0.f, 0.f, 0.f, 0.f);
    for (int k4 = 0; k4 < 32; ++k4) {
        const float4 w0 = *(const float4*)&w[(k4*4+0)*16 + c];
        const float4 w1 = *(const float4*)&w[(k4*4+1)*16 + c];
        const float4 w2 = *(const float4*)&w[(k4*4+2)*16 + c];
        const float4 w3 = *(const float4*)&w[(k4*4+3)*16 + c];
        const float4 xv = *(const float4*)&xs[r * 132 + k4 * 4];
        acc.x += xv.x*w0.x + xv.y*w1.x + xv.z*w2.x + xv.w*w3.x;
        acc.y += xv.x*w0.y + xv.y*w1.y + xv.z*w2.y + xv.w*w3.y;
        acc.z += xv.x*w0.z + xv.y*w1.z + xv.z*w2.z + xv.w*w3.z;
        acc.w += xv.x*w0.w + xv.y*w1.w + xv.z*w2.w + xv.w*w3.w;
    }
    if (r < nrem) {
        const float4 bv = *(const float4*)&b[c];
        float4 o = make_float4(acc.x + bv.x, acc.y + bv.y, acc.z + bv.z, acc.w + bv.w);
        *(float4*)&outp[(size_t)(n0 + r) * 16 + c] = o;
    }
}

// ---------------- conv2 aggregation: 16 lanes/dst, R1-exact sequential order ---
// Single online-softmax stream per dst (bitwise identical to the R1 version
// that passed); adds batched src-id loads + depth-3 prefetch only.
__global__ __launch_bounds__(256) void k_conv2_agg(
    const float* __restrict__ xl2, const float* __restrict__ xr2,
    const float* __restrict__ att, const float* __restrict__ bias2,
    const int* __restrict__ rowp, const int* __restrict__ slist,
    float* __restrict__ h2)
{
    const int d = (blockIdx.x * 256 + threadIdx.x) >> 4;
    if (d >= NN) return;
    const int lane  = threadIdx.x & 63;
    const int cl    = lane & 15;
    const int gbase = lane & 48;          // this 16-lane group's base lane

    const float xr = xr2[(size_t)d * 16 + cl];
    const float at = att[cl];
    const int beg = rowp[d], end = rowp[d + 1];

    float m = NEG_INF, den = 0.f, acc = 0.f;

    for (int base = beg; base < end; base += 16) {
        const int n = min(16, end - base);
        int sv = (cl < n) ? slist[base + cl] : 0;
        float v0, v1, v2;
        { int s = __shfl(sv, gbase); v0 = xl2[(size_t)s * 16 + cl]; }
        v1 = v0; v2 = v0;
        if (n > 1) { int s = __shfl(sv, gbase + 1); v1 = xl2[(size_t)s * 16 + cl]; }
        if (n > 2) { int s = __shfl(sv, gbase + 2); v2 = xl2[(size_t)s * 16 + cl]; }
        for (int i = 0; i < n; ++i) {
            float vn = v0;
            if (i + 3 < n) { int s = __shfl(sv, gbase + i + 3);
                             vn = xl2[(size_t)s * 16 + cl]; }
            float p = at * lrelu_f(v0 + xr);
            p += __shfl_xor(p, 1);
            p += __shfl_xor(p, 2);
            p += __shfl_xor(p, 4);
            p += __shfl_xor(p, 8);
            float nm   = fmaxf(m, p);
            float corr = __expf(m - nm);
            float w    = __expf(p - nm);
            den = den * corr + w;
            acc = acc * corr + w * v0;
            m = nm;
            v0 = v1; v1 = v2; v2 = vn;
        }
    }
    float o = acc / (den + 1e-16f) + bias2[cl];
    h2[(size_t)d * 16 + cl] = elu_f(o);
}

// ---------------- global mean pool (atomics) -----------------------------------
__global__ void k_pool(const float* __restrict__ h2, const int* __restrict__ batch,
                       float* __restrict__ pooled, float* __restrict__ cnt)
{
    int i = blockIdx.x * 256 + threadIdx.x;
    if (i >= NN * 16) return;
    int n = i >> 4, c = i & 15;
    int b = batch[n];
    atomicAdd(&pooled[b * 16 + c], h2[i]);
    if (c == 0) atomicAdd(&cnt[b], 1.0f);
}

// ---------------- MLP head: one thread per graph -------------------------------
__global__ __launch_bounds__(256) void k_mlp(
    const float* __restrict__ pooled, const float* __restrict__ cnt,
    const float* __restrict__ w1, const float* __restrict__ b1,
    const float* __restrict__ w2, const float* __restrict__ b2,
    const float* __restrict__ w3, const float* __restrict__ b3,
    float* __restrict__ out)
{
    __shared__ float w1s[16*32], w2s[32*16], w3s[16*32], b1s[32], b2s[16], b3s[32];
    const int tid = threadIdx.x;
    for (int i = tid; i < 512; i += 256) { w1s[i] = w1[i]; w2s[i] = w2[i]; w3s[i] = w3[i]; }
    if (tid < 32) b1s[tid] = b1[tid];
    if (tid < 16) b2s[tid] = b2[tid];
    if (tid < 32) b3s[tid] = b3[tid];
    __syncthreads();

    const int g = tid;  // graph id, 0..255
    const float inv = 1.0f / fmaxf(cnt[g], 1.0f);
    float hb[16];
#pragma unroll
    for (int k = 0; k < 16; ++k) hb[k] = pooled[g * 16 + k] * inv;

    float t1[32];
#pragma unroll
    for (int j = 0; j < 32; ++j) t1[j] = b1s[j];
    for (int k = 0; k < 16; ++k)
#pragma unroll
        for (int j = 0; j < 32; ++j) t1[j] += hb[k] * w1s[k * 32 + j];
#pragma unroll
    for (int j = 0; j < 32; ++j) t1[j] = elu_f(t1[j]);

    float t2[16];
#pragma unroll
    for (int j = 0; j < 16; ++j) t2[j] = b2s[j];
    for (int k = 0; k < 32; ++k)
#pragma unroll
        for (int j = 0; j < 16; ++j) t2[j] += t1[k] * w2s[k * 16 + j];
#pragma unroll
    for (int j = 0; j < 16; ++j) t2[j] = elu_f(t2[j]);

#pragma unroll
    for (int j = 0; j < 32; ++j) {
        float o = b3s[j];
        for (int k = 0; k < 16; ++k) o += t2[k] * w3s[k * 32 + j];
        out[g * 32 + j] = o;
    }
}

// ---------------- launch -------------------------------------------------------
extern "C" void kernel_launch(void* const* d_in, const int* in_sizes, int n_in,
                              void* d_out, int out_size, void* d_ws, size_t ws_size,
                              hipStream_t stream)
{
    const float* x     = (const float*)d_in[0];
    const int*   ei    = (const int*)d_in[1];
    const int*   batch = (const int*)d_in[2];
    const float* wl1   = (const float*)d_in[3];
    const float* bl1   = (const float*)d_in[4];
    const float* wr1   = (const float*)d_in[5];
    const float* br1   = (const float*)d_in[6];
    const float* att1  = (const float*)d_in[7];
    const float* bias1 = (const float*)d_in[8];
    const float* wl2   = (const float*)d_in[9];
    const float* bl2   = (const float*)d_in[10];
    const float* wr2   = (const float*)d_in[11];
    const float* br2   = (const float*)d_in[12];
    const float* att2  = (const float*)d_in[13];
    const float* bias2 = (const float*)d_in[14];
    const float* wm1   = (const float*)d_in[15];
    const float* bm1   = (const float*)d_in[16];
    const float* wm2   = (const float*)d_in[17];
    const float* bm2   = (const float*)d_in[18];
    const float* wm3   = (const float*)d_in[19];
    const float* bm3   = (const float*)d_in[20];
    float* out = (float*)d_out;

    char* base = (char*)d_ws;
    size_t off = 0;
    auto alloc = [&](size_t bytes) -> void* {
        void* p = base + off;
        off += (bytes + 255) & ~(size_t)255;
        return p;
    };
    float* xl1   = (float*)alloc((size_t)NN * 128 * 4);
    float* xr1   = (float*)alloc((size_t)NN * 128 * 4);
    float* h1    = (float*)alloc((size_t)NN * 128 * 4);
    int*   slist = (int*)  alloc((size_t)EP * 4);
    int*   rowp  = (int*)  alloc((size_t)(NN + 1) * 4);
    int*   cursor= (int*)  alloc((size_t)NN * 4);
    char*  zbase = base + off;                 // contiguous zero region start
    int*   counts= (int*)  alloc((size_t)NN * 4);
    float* pooled= (float*)alloc((size_t)NB * 16 * 4);
    float* cnt   = (float*)alloc((size_t)NB * 4);
    size_t zbytes = (size_t)((base + off) - zbase);
    // conv2 tensors reuse xl1's region (dead after k_conv1_agg)
    float* xl2 = xl1;
    float* xr2 = xl1 + (size_t)NN * 16;
    float* h2  = xl1 + (size_t)NN * 32;

    hipMemsetAsync(zbase, 0, zbytes, stream);
    k_gemm1<<<(NN + 31) / 32, 256, 0, stream>>>(x, wl1, bl1, wr1, br1, xl1, xr1);
    k_count<<<(EP + 255) / 256, 256, 0, stream>>>(ei, counts);
    k_scan<<<1, 1024, 0, stream>>>(counts, rowp, cursor);
    k_fill<<<(EP + 255) / 256, 256, 0, stream>>>(ei, cursor, slist);
    k_conv1_agg<<<(NN * 64) / 256, 256, 0, stream>>>(xl1, xr1, att1, bias1, rowp, slist, h1);
    k_gemm2<<<(NN + 31) / 32, 256, 0, stream>>>(h1, wl2, bl2, wr2, br2, xl2, xr2);
    k_conv2_agg<<<(NN * 16) / 256, 256, 0, stream>>>(xl2, xr2, att2, bias2, rowp, slist, h2);
    k_pool<<<(NN * 16 + 255) / 256, 256, 0, stream>>>(h2, batch, pooled, cnt);
    k_mlp<<<1, 256, 0, stream>>>(pooled, cnt, wm1, bm1, wm2, bm2, wm3, bm3, out);
}

// Round 4
// 671.045 us; speedup vs baseline: 1.5191x; 1.1657x over previous
//
#include <hip/hip_runtime.h>
#include <hip/hip_bf16.h>
#include <math.h>

#define NN   50000
#define NE   1600000
#define EP   (NE + NN)       // edges + self loops = 1,650,000
#define NB   256
#define NE4  (NE / 4)        // 400000, exact

__device__ __forceinline__ float elu_f(float x)   { return x > 0.0f ? x : expm1f(x); }
// leaky_relu(x, 0.2) == max(x, 0.2x) since 0.2 > 0
__device__ __forceinline__ float lrelu_f(float x) { return fmaxf(x, 0.2f * x); }

// ---------------- GEMM1: xl1 = x@wl1+bl1, xr1 = x@wr1+br1  ([N,64]x[64,128]) ----
__global__ __launch_bounds__(256) void k_gemm1(
    const float* __restrict__ x, const float* __restrict__ wl,
    const float* __restrict__ bl, const float* __restrict__ wr,
    const float* __restrict__ br, float* __restrict__ xl1, float* __restrict__ xr1)
{
    __shared__ float xs[32 * 64];
    const int tid = threadIdx.x;
    const int n0  = blockIdx.x * 32;
    const int nrem = min(32, NN - n0);

    const float4* xg = (const float4*)(x + (size_t)n0 * 64);
    float4* xs4 = (float4*)xs;
    const int lim4 = nrem * 16;
    for (int i = tid; i < lim4; i += 256) xs4[i] = xg[i];
    __syncthreads();

    const int g  = tid >> 6;        // 0..3 -> rows 8g..8g+7
    const int c0 = (tid & 63) * 4;  // 0..252
    const float* w; const float* b; float* outp; int cw;
    if (c0 < 128) { w = wl; b = bl; outp = xl1; cw = c0; }
    else          { w = wr; b = br; outp = xr1; cw = c0 - 128; }

    float4 acc[8];
#pragma unroll
    for (int r = 0; r < 8; ++r) acc[r] = make_float4(0.f, 0.f, 0.f, 0.f);

    for (int k4 = 0; k4 < 16; ++k4) {
        const float4 w0 = *(const float4*)&w[(k4*4+0)*128 + cw];
        const float4 w1 = *(const float4*)&w[(k4*4+1)*128 + cw];
        const float4 w2 = *(const float4*)&w[(k4*4+2)*128 + cw];
        const float4 w3 = *(const float4*)&w[(k4*4+3)*128 + cw];
#pragma unroll
        for (int r = 0; r < 8; ++r) {
            const float4 xv = xs4[(g*8+r)*16 + k4];
            acc[r].x += xv.x*w0.x + xv.y*w1.x + xv.z*w2.x + xv.w*w3.x;
            acc[r].y += xv.x*w0.y + xv.y*w1.y + xv.z*w2.y + xv.w*w3.y;
            acc[r].z += xv.x*w0.z + xv.y*w1.z + xv.z*w2.z + xv.w*w3.z;
            acc[r].w += xv.x*w0.w + xv.y*w1.w + xv.z*w2.w + xv.w*w3.w;
        }
    }
    const float4 bv = *(const float4*)&b[cw];
#pragma unroll
    for (int r = 0; r < 8; ++r) {
        const int row = g*8 + r;
        if (row < nrem) {
            float4 o = make_float4(acc[r].x + bv.x, acc[r].y + bv.y,
                                   acc[r].z + bv.z, acc[r].w + bv.w);
            *(float4*)&outp[(size_t)(n0 + row) * 128 + cw] = o;
        }
    }
}

// ---------------- CSR build ----------------------------------------------------
// counts excludes self-loops (added as +1 in scanA). 4 edges/thread -> 4
// independent fire-and-forget atomics in flight per lane.
__global__ void k_count(const int* __restrict__ ei, int* __restrict__ counts)
{
    int t = blockIdx.x * 256 + threadIdx.x;
    if (t >= NE4) return;
    int4 d4 = *(const int4*)&ei[NE + t * 4];
    atomicAdd(&counts[d4.x], 1);
    atomicAdd(&counts[d4.y], 1);
    atomicAdd(&counts[d4.z], 1);
    atomicAdd(&counts[d4.w], 1);
}

// scanA: per-block (256) inclusive scan of (counts[i]+1); write in-block
// exclusive to rowp, block total to bsum.
__global__ __launch_bounds__(256) void k_scanA(const int* __restrict__ counts,
                                               int* __restrict__ rowp,
                                               int* __restrict__ bsum)
{
    __shared__ int sm[256];
    const int t = threadIdx.x;
    const int i = blockIdx.x * 256 + t;
    const int c = (i < NN) ? counts[i] + 1 : 0;
    sm[t] = c;
    __syncthreads();
    for (int ofs = 1; ofs < 256; ofs <<= 1) {
        int v = (t >= ofs) ? sm[t - ofs] : 0;
        __syncthreads();
        sm[t] += v;
        __syncthreads();
    }
    if (i < NN) rowp[i] = sm[t] - c;
    if (t == 255) bsum[blockIdx.x] = sm[t];
}

// scanB: single block scans the 196 block sums -> exclusive offsets.
__global__ __launch_bounds__(256) void k_scanB(const int* __restrict__ bsum,
                                               int* __restrict__ boff, int nblk)
{
    __shared__ int sm[256];
    const int t = threadIdx.x;
    const int c = (t < nblk) ? bsum[t] : 0;
    sm[t] = c;
    __syncthreads();
    for (int ofs = 1; ofs < 256; ofs <<= 1) {
        int v = (t >= ofs) ? sm[t - ofs] : 0;
        __syncthreads();
        sm[t] += v;
        __syncthreads();
    }
    if (t < nblk) boff[t] = sm[t] - c;
}

// scanC: add block offsets; init cursor; rowp[NN]=EP.
__global__ void k_scanC(int* __restrict__ rowp, const int* __restrict__ boff,
                        int* __restrict__ cursor)
{
    int i = blockIdx.x * 256 + threadIdx.x;
    if (i >= NN) return;
    int r = rowp[i] + boff[i >> 8];
    rowp[i] = r;
    cursor[i] = r;
    if (i == 0) rowp[NN] = EP;
}

// fill: slist[pos] = source node, dst-sorted. 4 edges/thread (int4 loads);
// tail threads place the self-loops.
__global__ void k_fill(const int* __restrict__ ei, int* __restrict__ cursor,
                       int* __restrict__ slist)
{
    int t = blockIdx.x * 256 + threadIdx.x;
    if (t < NE4) {
        int4 s4 = *(const int4*)&ei[t * 4];
        int4 d4 = *(const int4*)&ei[NE + t * 4];
        int p0 = atomicAdd(&cursor[d4.x], 1);
        int p1 = atomicAdd(&cursor[d4.y], 1);
        int p2 = atomicAdd(&cursor[d4.z], 1);
        int p3 = atomicAdd(&cursor[d4.w], 1);
        slist[p0] = s4.x;
        slist[p1] = s4.y;
        slist[p2] = s4.z;
        slist[p3] = s4.w;
    } else if (t < NE4 + NN) {
        int d = t - NE4;                  // self loop
        int pos = atomicAdd(&cursor[d], 1);
        slist[pos] = d;
    }
}

// ---------------- conv1 aggregation: one wave per dst --------------------------
// lane = (h = lane>>3, e = lane&7): lane owns head h, edge-slot e -> 8 edges
// per iteration, each lane reads a full 16-ch head row as 4x float4.
// Softmax without max-subtraction (logits bounded; identical in exact math);
// 8 edge streams merged by a static register reduce-scatter over e.
__global__ __launch_bounds__(256) void k_conv1_agg(
    const float* __restrict__ xl1, const float* __restrict__ xr1,
    const float* __restrict__ att, const float* __restrict__ bias1,
    const int* __restrict__ rowp, const int* __restrict__ slist,
    float* __restrict__ h1)
{
    const int d = (blockIdx.x * 256 + threadIdx.x) >> 6;   // wave id = dst
    if (d >= NN) return;
    const int lane = threadIdx.x & 63;
    const int h = lane >> 3, e = lane & 7;
    const int cb = h * 16;

    const float4* xrp = (const float4*)&xr1[(size_t)d * 128 + cb];
    const float4 xr0 = xrp[0], xr1v = xrp[1], xr2v = xrp[2], xr3v = xrp[3];
    const float4* atp = (const float4*)&att[cb];
    const float4 at0 = atp[0], at1 = atp[1], at2 = atp[2], at3 = atp[3];

    const int beg = rowp[d], end = rowp[d + 1];

    float den = 0.f;
    float a[16];
#pragma unroll
    for (int c = 0; c < 16; ++c) a[c] = 0.f;

    for (int base = beg; base < end; base += 64) {
        const int nb = min(64, end - base);
        int sv = (lane < nb) ? slist[base + lane] : 0;
        for (int c8 = 0; c8 * 8 < nb; ++c8) {
            const int idx = c8 * 8 + e;
            const int src = __shfl(sv, idx);      // idx <= 63 always
            if (idx < nb) {
                const float4* vp = (const float4*)&xl1[(size_t)src * 128 + cb];
                const float4 v0 = vp[0], v1 = vp[1], v2 = vp[2], v3 = vp[3];
                float p;
                {
                    float t, s;
                    t = v0.x + xr0.x;  s  = at0.x * lrelu_f(t);
                    t = v0.y + xr0.y;  s += at0.y * lrelu_f(t);
                    t = v0.z + xr0.z;  s += at0.z * lrelu_f(t);
                    t = v0.w + xr0.w;  s += at0.w * lrelu_f(t);
                    t = v1.x + xr1v.x; s += at1.x * lrelu_f(t);
                    t = v1.y + xr1v.y; s += at1.y * lrelu_f(t);
                    t = v1.z + xr1v.z; s += at1.z * lrelu_f(t);
                    t = v1.w + xr1v.w; s += at1.w * lrelu_f(t);
                    t = v2.x + xr2v.x; s += at2.x * lrelu_f(t);
                    t = v2.y + xr2v.y; s += at2.y * lrelu_f(t);
                    t = v2.z + xr2v.z; s += at2.z * lrelu_f(t);
                    t = v2.w + xr2v.w; s += at2.w * lrelu_f(t);
                    t = v3.x + xr3v.x; s += at3.x * lrelu_f(t);
                    t = v3.y + xr3v.y; s += at3.y * lrelu_f(t);
                    t = v3.z + xr3v.z; s += at3.z * lrelu_f(t);
                    t = v3.w + xr3v.w; s += at3.w * lrelu_f(t);
                    p = s;
                }
                const float w = __expf(fminf(p, 80.f));
                den += w;
                a[0]  += w * v0.x;  a[1]  += w * v0.y;
                a[2]  += w * v0.z;  a[3]  += w * v0.w;
                a[4]  += w * v1.x;  a[5]  += w * v1.y;
                a[6]  += w * v1.z;  a[7]  += w * v1.w;
                a[8]  += w * v2.x;  a[9]  += w * v2.y;
                a[10] += w * v2.z;  a[11] += w * v2.w;
                a[12] += w * v3.x;  a[13] += w * v3.y;
                a[14] += w * v3.z;  a[15] += w * v3.w;
            }
        }
    }

    // sum den over the 8 e-lanes of this head
    den += __shfl_xor(den, 1);
    den += __shfl_xor(den, 2);
    den += __shfl_xor(den, 4);

    // reduce-scatter a[16] over e-lanes: each level halves the channel set
    const bool b0 = (e & 1), b1 = (e & 2), b2 = (e & 4);
    float t1[8], u1[8];
#pragma unroll
    for (int j = 0; j < 8; ++j) {
        t1[j] = b0 ? a[j + 8] : a[j];
        u1[j] = b0 ? a[j] : a[j + 8];
    }
#pragma unroll
    for (int j = 0; j < 8; ++j) t1[j] += __shfl_xor(u1[j], 1);
    float t2[4], u2[4];
#pragma unroll
    for (int j = 0; j < 4; ++j) {
        t2[j] = b1 ? t1[j + 4] : t1[j];
        u2[j] = b1 ? t1[j] : t1[j + 4];
    }
#pragma unroll
    for (int j = 0; j < 4; ++j) t2[j] += __shfl_xor(u2[j], 2);
    float t3[2], u3[2];
#pragma unroll
    for (int j = 0; j < 2; ++j) {
        t3[j] = b2 ? t2[j + 2] : t2[j];
        u3[j] = b2 ? t2[j] : t2[j + 2];
    }
#pragma unroll
    for (int j = 0; j < 2; ++j) t3[j] += __shfl_xor(u3[j], 4);

    const int c0 = (b0 ? 8 : 0) + (b1 ? 4 : 0) + (b2 ? 2 : 0);
    const float inv = 1.0f / (den + 1e-16f);
    const int c = cb + c0;
    const float o0 = elu_f(t3[0] * inv + bias1[c]);
    const float o1 = elu_f(t3[1] * inv + bias1[c + 1]);
    *(float2*)&h1[(size_t)d * 128 + c] = make_float2(o0, o1);
}

// ---------------- GEMM2: xl2 = h1@wl2+bl2, xr2 = h1@wr2+br2 ([N,128]x[128,16]) -
__global__ __launch_bounds__(256) void k_gemm2(
    const float* __restrict__ h1, const float* __restrict__ wl,
    const float* __restrict__ bl, const float* __restrict__ wr,
    const float* __restrict__ br, float* __restrict__ xl2, float* __restrict__ xr2)
{
    __shared__ float xs[32 * 132];
    const int tid = threadIdx.x;
    const int n0  = blockIdx.x * 32;
    const int nrem = min(32, NN - n0);

    for (int i = tid; i < nrem * 128; i += 256) {
        int row = i >> 7, col = i & 127;
        xs[row * 132 + col] = h1[(size_t)(n0 + row) * 128 + col];
    }
    __syncthreads();

    const int r  = tid >> 3;        // 0..31
    const int c0 = (tid & 7) * 4;   // 0..28
    const float* w; const float* b; float* outp; int c;
    if (c0 < 16) { w = wl; b = bl; outp = xl2; c = c0; }
    else         { w = wr; b = br; outp = xr2; c = c0 - 16; }

    float4 acc = make_float4(0.f, 0.f, 0.f, 0.f);
    for (int k4 = 0; k4 < 32; ++k4) {
        const float4 w0 = *(const float4*)&w[(k4*4+0)*16 + c];
        const float4 w1 = *(const float4*)&w[(k4*4+1)*16 + c];
        const float4 w2 = *(const float4*)&w[(k4*4+2)*16 + c];
        const float4 w3 = *(const float4*)&w[(k4*4+3)*16 + c];
        const float4 xv = *(const float4*)&xs[r * 132 + k4 * 4];
        acc.x += xv.x*w0.x + xv.y*w1.x + xv.z*w2.x + xv.w*w3.x;
        acc.y += xv.x*w0.y + xv.y*w1.y + xv.z*w2.y + xv.w*w3.y;
        acc.z += xv.x*w0.z + xv.y*w1.z + xv.z*w2.z + xv.w*w3.z;
        acc.w += xv.x*w0.w + xv.y*w1.w + xv.z*w2.w + xv.w*w3.w;
    }
    if (r < nrem) {
        const float4 bv = *(const float4*)&b[c];
        float4 o = make_float4(acc.x + bv.x, acc.y + bv.y, acc.z + bv.z, acc.w + bv.w);
        *(float4*)&outp[(size_t)(n0 + r) * 16 + c] = o;
    }
}

// ---------------- conv2 aggregation + fused mean-pool --------------------------
// One wave per dst. lane = (eq = lane>>2 edge slot, c4 = lane&3 channel quad):
// 16 edges/iteration; dot reduced over the 4 c4-lanes (xor 1,2 — uniform within
// quad); 16 edge streams merged by plain sum (xor 4..32). Epilogue atomicAdds
// into pooled/cnt (h2 buffer and k_pool eliminated).
__global__ __launch_bounds__(256) void k_conv2_agg(
    const float* __restrict__ xl2, const float* __restrict__ xr2,
    const float* __restrict__ att, const float* __restrict__ bias2,
    const int* __restrict__ rowp, const int* __restrict__ slist,
    const int* __restrict__ batch,
    float* __restrict__ pooled, float* __restrict__ cnt)
{
    const int d = (blockIdx.x * 256 + threadIdx.x) >> 6;   // wave id = dst
    if (d >= NN) return;
    const int lane = threadIdx.x & 63;
    const int eq = lane >> 2, c4 = lane & 3;

    const float4 xr = *(const float4*)&xr2[(size_t)d * 16 + c4 * 4];
    const float4 at = *(const float4*)&att[c4 * 4];
    const int beg = rowp[d], end = rowp[d + 1];

    float den = 0.f;
    float4 acc = make_float4(0.f, 0.f, 0.f, 0.f);

    for (int base = beg; base < end; base += 64) {
        const int nb = min(64, end - base);
        int sv = (lane < nb) ? slist[base + lane] : 0;
        for (int c16 = 0; c16 * 16 < nb; ++c16) {
            const int idx = c16 * 16 + eq;
            const int src = __shfl(sv, idx & 63);
            if (idx < nb) {
                const float4 v = *(const float4*)&xl2[(size_t)src * 16 + c4 * 4];
                float pp = at.x * lrelu_f(v.x + xr.x)
                         + at.y * lrelu_f(v.y + xr.y)
                         + at.z * lrelu_f(v.z + xr.z)
                         + at.w * lrelu_f(v.w + xr.w);
                pp += __shfl_xor(pp, 1);   // reduce over c4 quad (uniform within)
                pp += __shfl_xor(pp, 2);
                const float w = __expf(fminf(pp, 80.f));
                den += w;
                acc.x += w * v.x;
                acc.y += w * v.y;
                acc.z += w * v.z;
                acc.w += w * v.w;
            }
        }
    }
    // merge the 16 edge streams (lanes with same c4)
#pragma unroll
    for (int ofs = 4; ofs < 64; ofs <<= 1) {
        den   += __shfl_xor(den, ofs);
        acc.x += __shfl_xor(acc.x, ofs);
        acc.y += __shfl_xor(acc.y, ofs);
        acc.z += __shfl_xor(acc.z, ofs);
        acc.w += __shfl_xor(acc.w, ofs);
    }
    if (eq == 0) {
        const int b = batch[d];
        const float inv = 1.0f / (den + 1e-16f);
        const float4 bv = *(const float4*)&bias2[c4 * 4];
        float o0 = elu_f(acc.x * inv + bv.x);
        float o1 = elu_f(acc.y * inv + bv.y);
        float o2 = elu_f(acc.z * inv + bv.z);
        float o3 = elu_f(acc.w * inv + bv.w);
        float* pb = &pooled[b * 16 + c4 * 4];
        atomicAdd(pb + 0, o0);
        atomicAdd(pb + 1, o1);
        atomicAdd(pb + 2, o2);
        atomicAdd(pb + 3, o3);
        if (c4 == 0) atomicAdd(&cnt[b], 1.0f);
    }
}

// ---------------- MLP head: one thread per graph -------------------------------
__global__ __launch_bounds__(256) void k_mlp(
    const float* __restrict__ pooled, const float* __restrict__ cnt,
    const float* __restrict__ w1, const float* __restrict__ b1,
    const float* __restrict__ w2, const float* __restrict__ b2,
    const float* __restrict__ w3, const float* __restrict__ b3,
    float* __restrict__ out)
{
    __shared__ float w1s[16*32], w2s[32*16], w3s[16*32], b1s[32], b2s[16], b3s[32];
    const int tid = threadIdx.x;
    for (int i = tid; i < 512; i += 256) { w1s[i] = w1[i]; w2s[i] = w2[i]; w3s[i] = w3[i]; }
    if (tid < 32) b1s[tid] = b1[tid];
    if (tid < 16) b2s[tid] = b2[tid];
    if (tid < 32) b3s[tid] = b3[tid];
    __syncthreads();

    const int g = tid;  // graph id, 0..255
    const float inv = 1.0f / fmaxf(cnt[g], 1.0f);
    float hb[16];
#pragma unroll
    for (int k = 0; k < 16; ++k) hb[k] = pooled[g * 16 + k] * inv;

    float t1[32];
#pragma unroll
    for (int j = 0; j < 32; ++j) t1[j] = b1s[j];
    for (int k = 0; k < 16; ++k)
#pragma unroll
        for (int j = 0; j < 32; ++j) t1[j] += hb[k] * w1s[k * 32 + j];
#pragma unroll
    for (int j = 0; j < 32; ++j) t1[j] = elu_f(t1[j]);

    float t2[16];
#pragma unroll
    for (int j = 0; j < 16; ++j) t2[j] = b2s[j];
    for (int k = 0; k < 32; ++k)
#pragma unroll
        for (int j = 0; j < 16; ++j) t2[j] += t1[k] * w2s[k * 16 + j];
#pragma unroll
    for (int j = 0; j < 16; ++j) t2[j] = elu_f(t2[j]);

#pragma unroll
    for (int j = 0; j < 32; ++j) {
        float o = b3s[j];
        for (int k = 0; k < 16; ++k) o += t2[k] * w3s[k * 32 + j];
        out[g * 32 + j] = o;
    }
}

// ---------------- launch -------------------------------------------------------
extern "C" void kernel_launch(void* const* d_in, const int* in_sizes, int n_in,
                              void* d_out, int out_size, void* d_ws, size_t ws_size,
                              hipStream_t stream)
{
    const float* x     = (const float*)d_in[0];
    const int*   ei    = (const int*)d_in[1];
    const int*   batch = (const int*)d_in[2];
    const float* wl1   = (const float*)d_in[3];
    const float* bl1   = (const float*)d_in[4];
    const float* wr1   = (const float*)d_in[5];
    const float* br1   = (const float*)d_in[6];
    const float* att1  = (const float*)d_in[7];
    const float* bias1 = (const float*)d_in[8];
    const float* wl2   = (const float*)d_in[9];
    const float* bl2   = (const float*)d_in[10];
    const float* wr2   = (const float*)d_in[11];
    const float* br2   = (const float*)d_in[12];
    const float* att2  = (const float*)d_in[13];
    const float* bias2 = (const float*)d_in[14];
    const float* wm1   = (const float*)d_in[15];
    const float* bm1   = (const float*)d_in[16];
    const float* wm2   = (const float*)d_in[17];
    const float* bm2   = (const float*)d_in[18];
    const float* wm3   = (const float*)d_in[19];
    const float* bm3   = (const float*)d_in[20];
    float* out = (float*)d_out;

    char* base = (char*)d_ws;
    size_t off = 0;
    auto alloc = [&](size_t bytes) -> void* {
        void* p = base + off;
        off += (bytes + 255) & ~(size_t)255;
        return p;
    };
    float* xl1   = (float*)alloc((size_t)NN * 128 * 4);
    float* xr1   = (float*)alloc((size_t)NN * 128 * 4);
    float* h1    = (float*)alloc((size_t)NN * 128 * 4);
    int*   slist = (int*)  alloc((size_t)EP * 4);
    int*   rowp  = (int*)  alloc((size_t)(NN + 1) * 4);
    int*   cursor= (int*)  alloc((size_t)NN * 4);
    int*   bsum  = (int*)  alloc(256 * 4);
    int*   boff  = (int*)  alloc(256 * 4);
    char*  zbase = base + off;                 // contiguous zero region start
    int*   counts= (int*)  alloc((size_t)NN * 4);
    float* pooled= (float*)alloc((size_t)NB * 16 * 4);
    float* cnt   = (float*)alloc((size_t)NB * 4);
    size_t zbytes = (size_t)((base + off) - zbase);
    // conv2 tensors reuse xl1's region (dead after k_conv1_agg)
    float* xl2 = xl1;
    float* xr2 = xl1 + (size_t)NN * 16;

    const int SCAN_BLKS = (NN + 255) / 256;    // 196

    hipMemsetAsync(zbase, 0, zbytes, stream);
    k_gemm1<<<(NN + 31) / 32, 256, 0, stream>>>(x, wl1, bl1, wr1, br1, xl1, xr1);
    k_count<<<(NE4 + 255) / 256, 256, 0, stream>>>(ei, counts);
    k_scanA<<<SCAN_BLKS, 256, 0, stream>>>(counts, rowp, bsum);
    k_scanB<<<1, 256, 0, stream>>>(bsum, boff, SCAN_BLKS);
    k_scanC<<<SCAN_BLKS, 256, 0, stream>>>(rowp, boff, cursor);
    k_fill<<<(NE4 + NN + 255) / 256, 256, 0, stream>>>(ei, cursor, slist);
    k_conv1_agg<<<(NN * 64) / 256, 256, 0, stream>>>(xl1, xr1, att1, bias1, rowp, slist, h1);
    k_gemm2<<<(NN + 31) / 32, 256, 0, stream>>>(h1, wl2, bl2, wr2, br2, xl2, xr2);
    k_conv2_agg<<<(NN * 64) / 256, 256, 0, stream>>>(xl2, xr2, att2, bias2, rowp, slist,
                                                     batch, pooled, cnt);
    k_mlp<<<1, 256, 0, stream>>>(pooled, cnt, wm1, bm1, wm2, bm2, wm3, bm3, out);
}

// Round 5
// 556.192 us; speedup vs baseline: 1.8327x; 1.2065x over previous
//
#include <hip/hip_runtime.h>
#include <hip/hip_bf16.h>
#include <math.h>

#define NN   50000
#define NE   1600000
#define EP   (NE + NN)       // edges + self loops = 1,650,000
#define NB   256
#define NE8  (NE / 8)        // 200000, exact

__device__ __forceinline__ float elu_f(float x)   { return x > 0.0f ? x : expm1f(x); }
// leaky_relu(x, 0.2) == max(x, 0.2x) since 0.2 > 0
__device__ __forceinline__ float lrelu_f(float x) { return fmaxf(x, 0.2f * x); }

// ---------------- GEMM1: xl1 = x@wl1+bl1, xr1 = x@wr1+br1  ([N,64]x[64,128]) ----
__global__ __launch_bounds__(256) void k_gemm1(
    const float* __restrict__ x, const float* __restrict__ wl,
    const float* __restrict__ bl, const float* __restrict__ wr,
    const float* __restrict__ br, float* __restrict__ xl1, float* __restrict__ xr1)
{
    __shared__ float xs[32 * 64];
    const int tid = threadIdx.x;
    const int n0  = blockIdx.x * 32;
    const int nrem = min(32, NN - n0);

    const float4* xg = (const float4*)(x + (size_t)n0 * 64);
    float4* xs4 = (float4*)xs;
    const int lim4 = nrem * 16;
    for (int i = tid; i < lim4; i += 256) xs4[i] = xg[i];
    __syncthreads();

    const int g  = tid >> 6;        // 0..3 -> rows 8g..8g+7
    const int c0 = (tid & 63) * 4;  // 0..252
    const float* w; const float* b; float* outp; int cw;
    if (c0 < 128) { w = wl; b = bl; outp = xl1; cw = c0; }
    else          { w = wr; b = br; outp = xr1; cw = c0 - 128; }

    float4 acc[8];
#pragma unroll
    for (int r = 0; r < 8; ++r) acc[r] = make_float4(0.f, 0.f, 0.f, 0.f);

    for (int k4 = 0; k4 < 16; ++k4) {
        const float4 w0 = *(const float4*)&w[(k4*4+0)*128 + cw];
        const float4 w1 = *(const float4*)&w[(k4*4+1)*128 + cw];
        const float4 w2 = *(const float4*)&w[(k4*4+2)*128 + cw];
        const float4 w3 = *(const float4*)&w[(k4*4+3)*128 + cw];
#pragma unroll
        for (int r = 0; r < 8; ++r) {
            const float4 xv = xs4[(g*8+r)*16 + k4];
            acc[r].x += xv.x*w0.x + xv.y*w1.x + xv.z*w2.x + xv.w*w3.x;
            acc[r].y += xv.x*w0.y + xv.y*w1.y + xv.z*w2.y + xv.w*w3.y;
            acc[r].z += xv.x*w0.z + xv.y*w1.z + xv.z*w2.z + xv.w*w3.z;
            acc[r].w += xv.x*w0.w + xv.y*w1.w + xv.z*w2.w + xv.w*w3.w;
        }
    }
    const float4 bv = *(const float4*)&b[cw];
#pragma unroll
    for (int r = 0; r < 8; ++r) {
        const int row = g*8 + r;
        if (row < nrem) {
            float4 o = make_float4(acc[r].x + bv.x, acc[r].y + bv.y,
                                   acc[r].z + bv.z, acc[r].w + bv.w);
            *(float4*)&outp[(size_t)(n0 + row) * 128 + cw] = o;
        }
    }
}

// ---------------- CSR build ----------------------------------------------------
// counts excludes self-loops (added as +1 in scanA). 8 edges/thread -> 8
// independent fire-and-forget atomics in flight per lane.
__global__ void k_count(const int* __restrict__ ei, int* __restrict__ counts)
{
    int t = blockIdx.x * 256 + threadIdx.x;
    if (t >= NE8) return;
    int4 a = *(const int4*)&ei[NE + t * 8];
    int4 b = *(const int4*)&ei[NE + t * 8 + 4];
    atomicAdd(&counts[a.x], 1);
    atomicAdd(&counts[a.y], 1);
    atomicAdd(&counts[a.z], 1);
    atomicAdd(&counts[a.w], 1);
    atomicAdd(&counts[b.x], 1);
    atomicAdd(&counts[b.y], 1);
    atomicAdd(&counts[b.z], 1);
    atomicAdd(&counts[b.w], 1);
}

// scanA: per-block (256) inclusive scan of (counts[i]+1); write in-block
// exclusive to rowp, block total to bsum.
__global__ __launch_bounds__(256) void k_scanA(const int* __restrict__ counts,
                                               int* __restrict__ rowp,
                                               int* __restrict__ bsum)
{
    __shared__ int sm[256];
    const int t = threadIdx.x;
    const int i = blockIdx.x * 256 + t;
    const int c = (i < NN) ? counts[i] + 1 : 0;
    sm[t] = c;
    __syncthreads();
    for (int ofs = 1; ofs < 256; ofs <<= 1) {
        int v = (t >= ofs) ? sm[t - ofs] : 0;
        __syncthreads();
        sm[t] += v;
        __syncthreads();
    }
    if (i < NN) rowp[i] = sm[t] - c;
    if (t == 255) bsum[blockIdx.x] = sm[t];
}

// scanB: single block scans the block sums -> exclusive offsets.
__global__ __launch_bounds__(256) void k_scanB(const int* __restrict__ bsum,
                                               int* __restrict__ boff, int nblk)
{
    __shared__ int sm[256];
    const int t = threadIdx.x;
    const int c = (t < nblk) ? bsum[t] : 0;
    sm[t] = c;
    __syncthreads();
    for (int ofs = 1; ofs < 256; ofs <<= 1) {
        int v = (t >= ofs) ? sm[t - ofs] : 0;
        __syncthreads();
        sm[t] += v;
        __syncthreads();
    }
    if (t < nblk) boff[t] = sm[t] - c;
}

// scanC: add block offsets; init cursor; rowp[NN]=EP.
__global__ void k_scanC(int* __restrict__ rowp, const int* __restrict__ boff,
                        int* __restrict__ cursor)
{
    int i = blockIdx.x * 256 + threadIdx.x;
    if (i >= NN) return;
    int r = rowp[i] + boff[i >> 8];
    rowp[i] = r;
    cursor[i] = r;
    if (i == 0) rowp[NN] = EP;
}

// fill: slist[pos] = source node, dst-sorted. 8 edges/thread (2x int4);
// tail threads place the self-loops.
__global__ void k_fill(const int* __restrict__ ei, int* __restrict__ cursor,
                       int* __restrict__ slist)
{
    int t = blockIdx.x * 256 + threadIdx.x;
    if (t < NE8) {
        int4 sa = *(const int4*)&ei[t * 8];
        int4 sb = *(const int4*)&ei[t * 8 + 4];
        int4 da = *(const int4*)&ei[NE + t * 8];
        int4 db = *(const int4*)&ei[NE + t * 8 + 4];
        int p0 = atomicAdd(&cursor[da.x], 1);
        int p1 = atomicAdd(&cursor[da.y], 1);
        int p2 = atomicAdd(&cursor[da.z], 1);
        int p3 = atomicAdd(&cursor[da.w], 1);
        int p4 = atomicAdd(&cursor[db.x], 1);
        int p5 = atomicAdd(&cursor[db.y], 1);
        int p6 = atomicAdd(&cursor[db.z], 1);
        int p7 = atomicAdd(&cursor[db.w], 1);
        slist[p0] = sa.x;
        slist[p1] = sa.y;
        slist[p2] = sa.z;
        slist[p3] = sa.w;
        slist[p4] = sb.x;
        slist[p5] = sb.y;
        slist[p6] = sb.z;
        slist[p7] = sb.w;
    } else if (t < NE8 + NN) {
        int d = t - NE8;                  // self loop
        int pos = atomicAdd(&cursor[d], 1);
        slist[pos] = d;
    }
}

// ---------------- conv1 aggregation: one wave per dst --------------------------
// lane = (h = lane>>3, e = lane&7): lane owns head h, edge-slot e -> 8 edges
// per iteration, each lane reads a full 16-ch head row as 4x float4.
__global__ __launch_bounds__(256) void k_conv1_agg(
    const float* __restrict__ xl1, const float* __restrict__ xr1,
    const float* __restrict__ att, const float* __restrict__ bias1,
    const int* __restrict__ rowp, const int* __restrict__ slist,
    float* __restrict__ h1)
{
    const int d = (blockIdx.x * 256 + threadIdx.x) >> 6;   // wave id = dst
    if (d >= NN) return;
    const int lane = threadIdx.x & 63;
    const int h = lane >> 3, e = lane & 7;
    const int cb = h * 16;

    const float4* xrp = (const float4*)&xr1[(size_t)d * 128 + cb];
    const float4 xr0 = xrp[0], xr1v = xrp[1], xr2v = xrp[2], xr3v = xrp[3];
    const float4* atp = (const float4*)&att[cb];
    const float4 at0 = atp[0], at1 = atp[1], at2 = atp[2], at3 = atp[3];

    const int beg = rowp[d], end = rowp[d + 1];

    float den = 0.f;
    float a[16];
#pragma unroll
    for (int c = 0; c < 16; ++c) a[c] = 0.f;

    for (int base = beg; base < end; base += 64) {
        const int nb = min(64, end - base);
        int sv = (lane < nb) ? slist[base + lane] : 0;
        for (int c8 = 0; c8 * 8 < nb; ++c8) {
            const int idx = c8 * 8 + e;
            const int src = __shfl(sv, idx);      // idx <= 63 always
            if (idx < nb) {
                const float4* vp = (const float4*)&xl1[(size_t)src * 128 + cb];
                const float4 v0 = vp[0], v1 = vp[1], v2 = vp[2], v3 = vp[3];
                float p;
                {
                    float t, s;
                    t = v0.x + xr0.x;  s  = at0.x * lrelu_f(t);
                    t = v0.y + xr0.y;  s += at0.y * lrelu_f(t);
                    t = v0.z + xr0.z;  s += at0.z * lrelu_f(t);
                    t = v0.w + xr0.w;  s += at0.w * lrelu_f(t);
                    t = v1.x + xr1v.x; s += at1.x * lrelu_f(t);
                    t = v1.y + xr1v.y; s += at1.y * lrelu_f(t);
                    t = v1.z + xr1v.z; s += at1.z * lrelu_f(t);
                    t = v1.w + xr1v.w; s += at1.w * lrelu_f(t);
                    t = v2.x + xr2v.x; s += at2.x * lrelu_f(t);
                    t = v2.y + xr2v.y; s += at2.y * lrelu_f(t);
                    t = v2.z + xr2v.z; s += at2.z * lrelu_f(t);
                    t = v2.w + xr2v.w; s += at2.w * lrelu_f(t);
                    t = v3.x + xr3v.x; s += at3.x * lrelu_f(t);
                    t = v3.y + xr3v.y; s += at3.y * lrelu_f(t);
                    t = v3.z + xr3v.z; s += at3.z * lrelu_f(t);
                    t = v3.w + xr3v.w; s += at3.w * lrelu_f(t);
                    p = s;
                }
                const float w = __expf(fminf(p, 80.f));
                den += w;
                a[0]  += w * v0.x;  a[1]  += w * v0.y;
                a[2]  += w * v0.z;  a[3]  += w * v0.w;
                a[4]  += w * v1.x;  a[5]  += w * v1.y;
                a[6]  += w * v1.z;  a[7]  += w * v1.w;
                a[8]  += w * v2.x;  a[9]  += w * v2.y;
                a[10] += w * v2.z;  a[11] += w * v2.w;
                a[12] += w * v3.x;  a[13] += w * v3.y;
                a[14] += w * v3.z;  a[15] += w * v3.w;
            }
        }
    }

    // sum den over the 8 e-lanes of this head
    den += __shfl_xor(den, 1);
    den += __shfl_xor(den, 2);
    den += __shfl_xor(den, 4);

    // reduce-scatter a[16] over e-lanes: each level halves the channel set
    const bool b0 = (e & 1), b1 = (e & 2), b2 = (e & 4);
    float t1[8], u1[8];
#pragma unroll
    for (int j = 0; j < 8; ++j) {
        t1[j] = b0 ? a[j + 8] : a[j];
        u1[j] = b0 ? a[j] : a[j + 8];
    }
#pragma unroll
    for (int j = 0; j < 8; ++j) t1[j] += __shfl_xor(u1[j], 1);
    float t2[4], u2[4];
#pragma unroll
    for (int j = 0; j < 4; ++j) {
        t2[j] = b1 ? t1[j + 4] : t1[j];
        u2[j] = b1 ? t1[j] : t1[j + 4];
    }
#pragma unroll
    for (int j = 0; j < 4; ++j) t2[j] += __shfl_xor(u2[j], 2);
    float t3[2], u3[2];
#pragma unroll
    for (int j = 0; j < 2; ++j) {
        t3[j] = b2 ? t2[j + 2] : t2[j];
        u3[j] = b2 ? t2[j] : t2[j + 2];
    }
#pragma unroll
    for (int j = 0; j < 2; ++j) t3[j] += __shfl_xor(u3[j], 4);

    const int c0 = (b0 ? 8 : 0) + (b1 ? 4 : 0) + (b2 ? 2 : 0);
    const float inv = 1.0f / (den + 1e-16f);
    const int c = cb + c0;
    const float o0 = elu_f(t3[0] * inv + bias1[c]);
    const float o1 = elu_f(t3[1] * inv + bias1[c + 1]);
    *(float2*)&h1[(size_t)d * 128 + c] = make_float2(o0, o1);
}

// ---------------- GEMM2: xl2 = h1@wl2+bl2, xr2 = h1@wr2+br2 ([N,128]x[128,16]) -
__global__ __launch_bounds__(256) void k_gemm2(
    const float* __restrict__ h1, const float* __restrict__ wl,
    const float* __restrict__ bl, const float* __restrict__ wr,
    const float* __restrict__ br, float* __restrict__ xl2, float* __restrict__ xr2)
{
    __shared__ float xs[32 * 132];
    const int tid = threadIdx.x;
    const int n0  = blockIdx.x * 32;
    const int nrem = min(32, NN - n0);

    for (int i = tid; i < nrem * 128; i += 256) {
        int row = i >> 7, col = i & 127;
        xs[row * 132 + col] = h1[(size_t)(n0 + row) * 128 + col];
    }
    __syncthreads();

    const int r  = tid >> 3;        // 0..31
    const int c0 = (tid & 7) * 4;   // 0..28
    const float* w; const float* b; float* outp; int c;
    if (c0 < 16) { w = wl; b = bl; outp = xl2; c = c0; }
    else         { w = wr; b = br; outp = xr2; c = c0 - 16; }

    float4 acc = make_float4(0.f, 0.f, 0.f, 0.f);
    for (int k4 = 0; k4 < 32; ++k4) {
        const float4 w0 = *(const float4*)&w[(k4*4+0)*16 + c];
        const float4 w1 = *(const float4*)&w[(k4*4+1)*16 + c];
        const float4 w2 = *(const float4*)&w[(k4*4+2)*16 + c];
        const float4 w3 = *(const float4*)&w[(k4*4+3)*16 + c];
        const float4 xv = *(const float4*)&xs[r * 132 + k4 * 4];
        acc.x += xv.x*w0.x + xv.y*w1.x + xv.z*w2.x + xv.w*w3.x;
        acc.y += xv.x*w0.y + xv.y*w1.y + xv.z*w2.y + xv.w*w3.y;
        acc.z += xv.x*w0.z + xv.y*w1.z + xv.z*w2.z + xv.w*w3.z;
        acc.w += xv.x*w0.w + xv.y*w1.w + xv.z*w2.w + xv.w*w3.w;
    }
    if (r < nrem) {
        const float4 bv = *(const float4*)&b[c];
        float4 o = make_float4(acc.x + bv.x, acc.y + bv.y, acc.z + bv.z, acc.w + bv.w);
        *(float4*)&outp[(size_t)(n0 + r) * 16 + c] = o;
    }
}

// ---------------- conv2 aggregation: one wave per dst, h2 output ---------------
// lane = (eq = lane>>2 edge slot, c4 = lane&3 channel quad): 16 edges/iter;
// dot reduced over the c4 quad (xor 1,2); 16 edge streams merged by plain sum.
// NO atomics in epilogue — coalesced 64 B h2 row store (R4's fused-pool atomics
// serialized the kernel on ~195-deep same-address chains).
__global__ __launch_bounds__(256) void k_conv2_agg(
    const float* __restrict__ xl2, const float* __restrict__ xr2,
    const float* __restrict__ att, const float* __restrict__ bias2,
    const int* __restrict__ rowp, const int* __restrict__ slist,
    float* __restrict__ h2)
{
    const int d = (blockIdx.x * 256 + threadIdx.x) >> 6;   // wave id = dst
    if (d >= NN) return;
    const int lane = threadIdx.x & 63;
    const int eq = lane >> 2, c4 = lane & 3;

    const float4 xr = *(const float4*)&xr2[(size_t)d * 16 + c4 * 4];
    const float4 at = *(const float4*)&att[c4 * 4];
    const int beg = rowp[d], end = rowp[d + 1];

    float den = 0.f;
    float4 acc = make_float4(0.f, 0.f, 0.f, 0.f);

    for (int base = beg; base < end; base += 64) {
        const int nb = min(64, end - base);
        int sv = (lane < nb) ? slist[base + lane] : 0;
        for (int c16 = 0; c16 * 16 < nb; ++c16) {
            const int idx = c16 * 16 + eq;
            const int src = __shfl(sv, idx & 63);
            if (idx < nb) {
                const float4 v = *(const float4*)&xl2[(size_t)src * 16 + c4 * 4];
                float pp = at.x * lrelu_f(v.x + xr.x)
                         + at.y * lrelu_f(v.y + xr.y)
                         + at.z * lrelu_f(v.z + xr.z)
                         + at.w * lrelu_f(v.w + xr.w);
                pp += __shfl_xor(pp, 1);   // reduce over c4 quad (uniform within)
                pp += __shfl_xor(pp, 2);
                const float w = __expf(fminf(pp, 80.f));
                den += w;
                acc.x += w * v.x;
                acc.y += w * v.y;
                acc.z += w * v.z;
                acc.w += w * v.w;
            }
        }
    }
    // merge the 16 edge streams (lanes with same c4)
#pragma unroll
    for (int ofs = 4; ofs < 64; ofs <<= 1) {
        den   += __shfl_xor(den, ofs);
        acc.x += __shfl_xor(acc.x, ofs);
        acc.y += __shfl_xor(acc.y, ofs);
        acc.z += __shfl_xor(acc.z, ofs);
        acc.w += __shfl_xor(acc.w, ofs);
    }
    if (eq == 0) {
        const float inv = 1.0f / (den + 1e-16f);
        const float4 bv = *(const float4*)&bias2[c4 * 4];
        float4 o;
        o.x = elu_f(acc.x * inv + bv.x);
        o.y = elu_f(acc.y * inv + bv.y);
        o.z = elu_f(acc.z * inv + bv.z);
        o.w = elu_f(acc.w * inv + bv.w);
        *(float4*)&h2[(size_t)d * 16 + c4 * 4] = o;   // lanes 0..3: 64 B row
    }
}

// ---------------- mean pool: one block per graph, zero atomics -----------------
// batch is sorted -> graph b's nodes are the contiguous range
// [lower_bound(b), lower_bound(b+1)). thread = (slot = tid>>4, c = tid&15).
__global__ __launch_bounds__(256) void k_pool(
    const float* __restrict__ h2, const int* __restrict__ batch,
    float* __restrict__ pooled, float* __restrict__ cnt)
{
    __shared__ int se[2];
    __shared__ float sm[256];
    const int b = blockIdx.x, tid = threadIdx.x;
    if (tid < 2) {
        int key = b + tid, lo = 0, hi = NN;
        while (lo < hi) {
            int mid = (lo + hi) >> 1;
            if (batch[mid] < key) lo = mid + 1; else hi = mid;
        }
        se[tid] = lo;
    }
    __syncthreads();
    const int s = se[0], e = se[1];
    const int c = tid & 15, slot = tid >> 4;
    float acc = 0.f;
    for (int n = s + slot; n < e; n += 16) acc += h2[(size_t)n * 16 + c];
    sm[tid] = acc;
    __syncthreads();
    for (int ofs = 128; ofs >= 16; ofs >>= 1) {
        if (tid < ofs) sm[tid] += sm[tid + ofs];
        __syncthreads();
    }
    if (tid < 16) pooled[b * 16 + tid] = sm[tid];
    if (tid == 16) cnt[b] = (float)(e - s);
}

// ---------------- MLP head: one thread per graph -------------------------------
__global__ __launch_bounds__(256) void k_mlp(
    const float* __restrict__ pooled, const float* __restrict__ cnt,
    const float* __restrict__ w1, const float* __restrict__ b1,
    const float* __restrict__ w2, const float* __restrict__ b2,
    const float* __restrict__ w3, const float* __restrict__ b3,
    float* __restrict__ out)
{
    __shared__ float w1s[16*32], w2s[32*16], w3s[16*32], b1s[32], b2s[16], b3s[32];
    const int tid = threadIdx.x;
    for (int i = tid; i < 512; i += 256) { w1s[i] = w1[i]; w2s[i] = w2[i]; w3s[i] = w3[i]; }
    if (tid < 32) b1s[tid] = b1[tid];
    if (tid < 16) b2s[tid] = b2[tid];
    if (tid < 32) b3s[tid] = b3[tid];
    __syncthreads();

    const int g = tid;  // graph id, 0..255
    const float inv = 1.0f / fmaxf(cnt[g], 1.0f);
    float hb[16];
#pragma unroll
    for (int k = 0; k < 16; ++k) hb[k] = pooled[g * 16 + k] * inv;

    float t1[32];
#pragma unroll
    for (int j = 0; j < 32; ++j) t1[j] = b1s[j];
    for (int k = 0; k < 16; ++k)
#pragma unroll
        for (int j = 0; j < 32; ++j) t1[j] += hb[k] * w1s[k * 32 + j];
#pragma unroll
    for (int j = 0; j < 32; ++j) t1[j] = elu_f(t1[j]);

    float t2[16];
#pragma unroll
    for (int j = 0; j < 16; ++j) t2[j] = b2s[j];
    for (int k = 0; k < 32; ++k)
#pragma unroll
        for (int j = 0; j < 16; ++j) t2[j] += t1[k] * w2s[k * 16 + j];
#pragma unroll
    for (int j = 0; j < 16; ++j) t2[j] = elu_f(t2[j]);

#pragma unroll
    for (int j = 0; j < 32; ++j) {
        float o = b3s[j];
        for (int k = 0; k < 16; ++k) o += t2[k] * w3s[k * 32 + j];
        out[g * 32 + j] = o;
    }
}

// ---------------- launch -------------------------------------------------------
extern "C" void kernel_launch(void* const* d_in, const int* in_sizes, int n_in,
                              void* d_out, int out_size, void* d_ws, size_t ws_size,
                              hipStream_t stream)
{
    const float* x     = (const float*)d_in[0];
    const int*   ei    = (const int*)d_in[1];
    const int*   batch = (const int*)d_in[2];
    const float* wl1   = (const float*)d_in[3];
    const float* bl1   = (const float*)d_in[4];
    const float* wr1   = (const float*)d_in[5];
    const float* br1   = (const float*)d_in[6];
    const float* att1  = (const float*)d_in[7];
    const float* bias1 = (const float*)d_in[8];
    const float* wl2   = (const float*)d_in[9];
    const float* bl2   = (const float*)d_in[10];
    const float* wr2   = (const float*)d_in[11];
    const float* br2   = (const float*)d_in[12];
    const float* att2  = (const float*)d_in[13];
    const float* bias2 = (const float*)d_in[14];
    const float* wm1   = (const float*)d_in[15];
    const float* bm1   = (const float*)d_in[16];
    const float* wm2   = (const float*)d_in[17];
    const float* bm2   = (const float*)d_in[18];
    const float* wm3   = (const float*)d_in[19];
    const float* bm3   = (const float*)d_in[20];
    float* out = (float*)d_out;

    char* base = (char*)d_ws;
    size_t off = 0;
    auto alloc = [&](size_t bytes) -> void* {
        void* p = base + off;
        off += (bytes + 255) & ~(size_t)255;
        return p;
    };
    float* xl1   = (float*)alloc((size_t)NN * 128 * 4);
    float* xr1   = (float*)alloc((size_t)NN * 128 * 4);
    float* h1    = (float*)alloc((size_t)NN * 128 * 4);
    int*   slist = (int*)  alloc((size_t)EP * 4);
    int*   rowp  = (int*)  alloc((size_t)(NN + 1) * 4);
    int*   cursor= (int*)  alloc((size_t)NN * 4);
    int*   bsum  = (int*)  alloc(256 * 4);
    int*   boff  = (int*)  alloc(256 * 4);
    int*   counts= (int*)  alloc((size_t)NN * 4);
    float* pooled= (float*)alloc((size_t)NB * 16 * 4);
    float* cnt   = (float*)alloc((size_t)NB * 4);
    // conv2 tensors reuse xl1's region (dead after k_conv1_agg)
    float* xl2 = xl1;
    float* xr2 = xl1 + (size_t)NN * 16;
    float* h2  = xl1 + (size_t)NN * 32;

    const int SCAN_BLKS = (NN + 255) / 256;    // 196

    hipMemsetAsync(counts, 0, (size_t)NN * 4, stream);   // only counts needs zeroing
    k_gemm1<<<(NN + 31) / 32, 256, 0, stream>>>(x, wl1, bl1, wr1, br1, xl1, xr1);
    k_count<<<(NE8 + 255) / 256, 256, 0, stream>>>(ei, counts);
    k_scanA<<<SCAN_BLKS, 256, 0, stream>>>(counts, rowp, bsum);
    k_scanB<<<1, 256, 0, stream>>>(bsum, boff, SCAN_BLKS);
    k_scanC<<<SCAN_BLKS, 256, 0, stream>>>(rowp, boff, cursor);
    k_fill<<<(NE8 + NN + 255) / 256, 256, 0, stream>>>(ei, cursor, slist);
    k_conv1_agg<<<(NN * 64) / 256, 256, 0, stream>>>(xl1, xr1, att1, bias1, rowp, slist, h1);
    k_gemm2<<<(NN + 31) / 32, 256, 0, stream>>>(h1, wl2, bl2, wr2, br2, xl2, xr2);
    k_conv2_agg<<<(NN * 64) / 256, 256, 0, stream>>>(xl2, xr2, att2, bias2, rowp, slist, h2);
    k_pool<<<NB, 256, 0, stream>>>(h2, batch, pooled, cnt);
    k_mlp<<<1, 256, 0, stream>>>(pooled, cnt, wm1, bm1, wm2, bm2, wm3, bm3, out);
}

// Round 6
// 396.035 us; speedup vs baseline: 2.5739x; 1.4044x over previous
//
#include <hip/hip_runtime.h>
#include <hip/hip_bf16.h>
#include <math.h>

#define NN   50000
#define NE   1600000
#define EP   (NE + NN)       // edges + self loops = 1,650,000
#define NB   256
#define BK_SH 7              // 128 dsts per bucket
#define NBKT ((NN + 127) >> BK_SH)   // 391
#define ET   32              // edges per thread in bucket kernels
#define EB   (256 * ET)      // 8192 edges per block
#define EBLK ((NE + EB - 1) / EB)    // 196 blocks (NE/EB exact? 1.6M/8192=195.3 -> 196)

__device__ __forceinline__ float elu_f(float x)   { return x > 0.0f ? x : expm1f(x); }
// leaky_relu(x, 0.2) == max(x, 0.2x) since 0.2 > 0
__device__ __forceinline__ float lrelu_f(float x) { return fmaxf(x, 0.2f * x); }

// ---------------- GEMM1: xl1 = x@wl1+bl1, xr1 = x@wr1+br1  ([N,64]x[64,128]) ----
__global__ __launch_bounds__(256) void k_gemm1(
    const float* __restrict__ x, const float* __restrict__ wl,
    const float* __restrict__ bl, const float* __restrict__ wr,
    const float* __restrict__ br, float* __restrict__ xl1, float* __restrict__ xr1)
{
    __shared__ float xs[32 * 64];
    const int tid = threadIdx.x;
    const int n0  = blockIdx.x * 32;
    const int nrem = min(32, NN - n0);

    const float4* xg = (const float4*)(x + (size_t)n0 * 64);
    float4* xs4 = (float4*)xs;
    const int lim4 = nrem * 16;
    for (int i = tid; i < lim4; i += 256) xs4[i] = xg[i];
    __syncthreads();

    const int g  = tid >> 6;        // 0..3 -> rows 8g..8g+7
    const int c0 = (tid & 63) * 4;  // 0..252
    const float* w; const float* b; float* outp; int cw;
    if (c0 < 128) { w = wl; b = bl; outp = xl1; cw = c0; }
    else          { w = wr; b = br; outp = xr1; cw = c0 - 128; }

    float4 acc[8];
#pragma unroll
    for (int r = 0; r < 8; ++r) acc[r] = make_float4(0.f, 0.f, 0.f, 0.f);

    for (int k4 = 0; k4 < 16; ++k4) {
        const float4 w0 = *(const float4*)&w[(k4*4+0)*128 + cw];
        const float4 w1 = *(const float4*)&w[(k4*4+1)*128 + cw];
        const float4 w2 = *(const float4*)&w[(k4*4+2)*128 + cw];
        const float4 w3 = *(const float4*)&w[(k4*4+3)*128 + cw];
#pragma unroll
        for (int r = 0; r < 8; ++r) {
            const float4 xv = xs4[(g*8+r)*16 + k4];
            acc[r].x += xv.x*w0.x + xv.y*w1.x + xv.z*w2.x + xv.w*w3.x;
            acc[r].y += xv.x*w0.y + xv.y*w1.y + xv.z*w2.y + xv.w*w3.y;
            acc[r].z += xv.x*w0.z + xv.y*w1.z + xv.z*w2.z + xv.w*w3.z;
            acc[r].w += xv.x*w0.w + xv.y*w1.w + xv.z*w2.w + xv.w*w3.w;
        }
    }
    const float4 bv = *(const float4*)&b[cw];
#pragma unroll
    for (int r = 0; r < 8; ++r) {
        const int row = g*8 + r;
        if (row < nrem) {
            float4 o = make_float4(acc[r].x + bv.x, acc[r].y + bv.y,
                                   acc[r].z + bv.z, acc[r].w + bv.w);
            *(float4*)&outp[(size_t)(n0 + row) * 128 + cw] = o;
        }
    }
}

// ---------------- CSR build via two-pass bucket sort ---------------------------
// Buckets of 128 consecutive dst ids. Self-loops are NOT in the bucket stream;
// k_bfinal adds them analytically (+1 per dst, slot 0 of each segment).

// bhist: LDS-aggregated histogram of edge dst buckets -> bcnt[NBKT]
__global__ __launch_bounds__(256) void k_bhist(const int* __restrict__ ei,
                                               int* __restrict__ bcnt)
{
    __shared__ int lh[NBKT];
    const int tid = threadIdx.x;
    for (int i = tid; i < NBKT; i += 256) lh[i] = 0;
    __syncthreads();
    const int t = blockIdx.x * 256 + tid;
    if (t * ET < NE) {
        const int4* dp = (const int4*)&ei[NE + t * ET];
#pragma unroll
        for (int q = 0; q < ET / 4; ++q) {
            int4 d = dp[q];
            atomicAdd(&lh[d.x >> BK_SH], 1);
            atomicAdd(&lh[d.y >> BK_SH], 1);
            atomicAdd(&lh[d.z >> BK_SH], 1);
            atomicAdd(&lh[d.w >> BK_SH], 1);
        }
    }
    __syncthreads();
    for (int i = tid; i < NBKT; i += 256) {
        int v = lh[i];
        if (v > 0) atomicAdd(&bcnt[i], v);
    }
}

// bscan: one block (512 thr) exclusive-scans bcnt -> bstart, bcursor
__global__ __launch_bounds__(512) void k_bscan(const int* __restrict__ bcnt,
                                               int* __restrict__ bstart,
                                               int* __restrict__ bcursor)
{
    __shared__ int sm[512];
    const int t = threadIdx.x;
    const int c = (t < NBKT) ? bcnt[t] : 0;
    sm[t] = c;
    __syncthreads();
    for (int ofs = 1; ofs < 512; ofs <<= 1) {
        int v = (t >= ofs) ? sm[t - ofs] : 0;
        __syncthreads();
        sm[t] += v;
        __syncthreads();
    }
    if (t < NBKT) {
        int ex = sm[t] - c;
        bstart[t] = ex;
        bcursor[t] = ex;
    }
    if (t == NBKT) bstart[NBKT] = NE;   // NBKT < 512
}

// bucket: scatter packed (dst<<32|src) into bucket regions. Per-block LDS
// histogram + one reserving global atomic per bucket -> contiguous per-block
// runs inside each bucket (write lines touched by one block only).
__global__ __launch_bounds__(256) void k_bucket(const int* __restrict__ ei,
                                                int* __restrict__ bcursor,
                                                unsigned long long* __restrict__ bb)
{
    __shared__ int lh[NBKT];
    __shared__ int cur[NBKT];
    const int tid = threadIdx.x;
    for (int i = tid; i < NBKT; i += 256) lh[i] = 0;
    __syncthreads();

    const int t = blockIdx.x * 256 + tid;
    const bool act = (t * ET < NE);
    int4 dreg[ET / 4];
    if (act) {
        const int4* dp = (const int4*)&ei[NE + t * ET];
#pragma unroll
        for (int q = 0; q < ET / 4; ++q) {
            dreg[q] = dp[q];
            atomicAdd(&lh[dreg[q].x >> BK_SH], 1);
            atomicAdd(&lh[dreg[q].y >> BK_SH], 1);
            atomicAdd(&lh[dreg[q].z >> BK_SH], 1);
            atomicAdd(&lh[dreg[q].w >> BK_SH], 1);
        }
    }
    __syncthreads();
    for (int i = tid; i < NBKT; i += 256) {
        int h = lh[i];
        if (h > 0) cur[i] = atomicAdd(&bcursor[i], h);
    }
    __syncthreads();
    if (act) {
        const int4* sp = (const int4*)&ei[t * ET];
#pragma unroll
        for (int q = 0; q < ET / 4; ++q) {
            int4 s = sp[q];
            int4 d = dreg[q];
            int p;
            p = atomicAdd(&cur[d.x >> BK_SH], 1);
            bb[p] = ((unsigned long long)(unsigned)d.x << 32) | (unsigned)s.x;
            p = atomicAdd(&cur[d.y >> BK_SH], 1);
            bb[p] = ((unsigned long long)(unsigned)d.y << 32) | (unsigned)s.y;
            p = atomicAdd(&cur[d.z >> BK_SH], 1);
            bb[p] = ((unsigned long long)(unsigned)d.z << 32) | (unsigned)s.z;
            p = atomicAdd(&cur[d.w >> BK_SH], 1);
            bb[p] = ((unsigned long long)(unsigned)d.w << 32) | (unsigned)s.w;
        }
    }
}

// bfinal: one block per bucket. Per-dst LDS count (+1 self-loop) -> scan ->
// rowp; then scatter slist within the bucket's contiguous output range.
// Global output start = bstart[b] (edges) + db0 (one self-loop per dst < db0).
__global__ __launch_bounds__(256) void k_bfinal(
    const unsigned long long* __restrict__ bb, const int* __restrict__ bstart,
    int* __restrict__ rowp, int* __restrict__ slist)
{
    __shared__ int cnt[128], off[128], cur[128];
    const int b = blockIdx.x, tid = threadIdx.x;
    const int db0 = b << BK_SH;
    const int dn  = min(128, NN - db0);
    const int ebeg = bstart[b], eend = bstart[b + 1];
    const int out0 = ebeg + db0;

    int c0 = 0;
    if (tid < 128) {
        c0 = (tid < dn) ? 1 : 0;       // self-loop
        cnt[tid] = c0;
    }
    __syncthreads();
    for (int i = ebeg + tid; i < eend; i += 256) {
        unsigned long long u = bb[i];
        int d = (int)(u >> 32) - db0;
        atomicAdd(&cnt[d], 1);
    }
    __syncthreads();
    if (tid < 128) c0 = cnt[tid];      // per-dst total (incl. self-loop)
    // inclusive scan of cnt[128]
    for (int ofs = 1; ofs < 128; ofs <<= 1) {
        int v = 0;
        if (tid < 128 && tid >= ofs) v = cnt[tid - ofs];
        __syncthreads();
        if (tid < 128) cnt[tid] += v;
        __syncthreads();
    }
    if (tid < 128) {
        int ex = cnt[tid] - c0;        // exclusive
        off[tid] = ex;
        cur[tid] = ex + 1;             // slot 0 reserved for self-loop
        if (tid < dn) {
            rowp[db0 + tid] = out0 + ex;
            slist[out0 + ex] = db0 + tid;   // self-loop
        }
    }
    if (b == 0 && tid == 0) rowp[NN] = EP;
    __syncthreads();
    for (int i = ebeg + tid; i < eend; i += 256) {
        unsigned long long u = bb[i];
        int d = (int)(u >> 32) - db0;
        int p = atomicAdd(&cur[d], 1);
        slist[out0 + p] = (int)(u & 0xffffffffu);
    }
}

// ---------------- conv1 aggregation: one wave per dst --------------------------
// lane = (h = lane>>3, e = lane&7): lane owns head h, edge-slot e -> 8 edges
// per iteration, each lane reads a full 16-ch head row as 4x float4.
__global__ __launch_bounds__(256) void k_conv1_agg(
    const float* __restrict__ xl1, const float* __restrict__ xr1,
    const float* __restrict__ att, const float* __restrict__ bias1,
    const int* __restrict__ rowp, const int* __restrict__ slist,
    float* __restrict__ h1)
{
    const int d = (blockIdx.x * 256 + threadIdx.x) >> 6;   // wave id = dst
    if (d >= NN) return;
    const int lane = threadIdx.x & 63;
    const int h = lane >> 3, e = lane & 7;
    const int cb = h * 16;

    const float4* xrp = (const float4*)&xr1[(size_t)d * 128 + cb];
    const float4 xr0 = xrp[0], xr1v = xrp[1], xr2v = xrp[2], xr3v = xrp[3];
    const float4* atp = (const float4*)&att[cb];
    const float4 at0 = atp[0], at1 = atp[1], at2 = atp[2], at3 = atp[3];

    const int beg = rowp[d], end = rowp[d + 1];

    float den = 0.f;
    float a[16];
#pragma unroll
    for (int c = 0; c < 16; ++c) a[c] = 0.f;

    for (int base = beg; base < end; base += 64) {
        const int nb = min(64, end - base);
        int sv = (lane < nb) ? slist[base + lane] : 0;
        for (int c8 = 0; c8 * 8 < nb; ++c8) {
            const int idx = c8 * 8 + e;
            const int src = __shfl(sv, idx);      // idx <= 63 always
            if (idx < nb) {
                const float4* vp = (const float4*)&xl1[(size_t)src * 128 + cb];
                const float4 v0 = vp[0], v1 = vp[1], v2 = vp[2], v3 = vp[3];
                float p;
                {
                    float t, s;
                    t = v0.x + xr0.x;  s  = at0.x * lrelu_f(t);
                    t = v0.y + xr0.y;  s += at0.y * lrelu_f(t);
                    t = v0.z + xr0.z;  s += at0.z * lrelu_f(t);
                    t = v0.w + xr0.w;  s += at0.w * lrelu_f(t);
                    t = v1.x + xr1v.x; s += at1.x * lrelu_f(t);
                    t = v1.y + xr1v.y; s += at1.y * lrelu_f(t);
                    t = v1.z + xr1v.z; s += at1.z * lrelu_f(t);
                    t = v1.w + xr1v.w; s += at1.w * lrelu_f(t);
                    t = v2.x + xr2v.x; s += at2.x * lrelu_f(t);
                    t = v2.y + xr2v.y; s += at2.y * lrelu_f(t);
                    t = v2.z + xr2v.z; s += at2.z * lrelu_f(t);
                    t = v2.w + xr2v.w; s += at2.w * lrelu_f(t);
                    t = v3.x + xr3v.x; s += at3.x * lrelu_f(t);
                    t = v3.y + xr3v.y; s += at3.y * lrelu_f(t);
                    t = v3.z + xr3v.z; s += at3.z * lrelu_f(t);
                    t = v3.w + xr3v.w; s += at3.w * lrelu_f(t);
                    p = s;
                }
                const float w = __expf(fminf(p, 80.f));
                den += w;
                a[0]  += w * v0.x;  a[1]  += w * v0.y;
                a[2]  += w * v0.z;  a[3]  += w * v0.w;
                a[4]  += w * v1.x;  a[5]  += w * v1.y;
                a[6]  += w * v1.z;  a[7]  += w * v1.w;
                a[8]  += w * v2.x;  a[9]  += w * v2.y;
                a[10] += w * v2.z;  a[11] += w * v2.w;
                a[12] += w * v3.x;  a[13] += w * v3.y;
                a[14] += w * v3.z;  a[15] += w * v3.w;
            }
        }
    }

    // sum den over the 8 e-lanes of this head
    den += __shfl_xor(den, 1);
    den += __shfl_xor(den, 2);
    den += __shfl_xor(den, 4);

    // reduce-scatter a[16] over e-lanes: each level halves the channel set
    const bool b0 = (e & 1), b1 = (e & 2), b2 = (e & 4);
    float t1[8], u1[8];
#pragma unroll
    for (int j = 0; j < 8; ++j) {
        t1[j] = b0 ? a[j + 8] : a[j];
        u1[j] = b0 ? a[j] : a[j + 8];
    }
#pragma unroll
    for (int j = 0; j < 8; ++j) t1[j] += __shfl_xor(u1[j], 1);
    float t2[4], u2[4];
#pragma unroll
    for (int j = 0; j < 4; ++j) {
        t2[j] = b1 ? t1[j + 4] : t1[j];
        u2[j] = b1 ? t1[j] : t1[j + 4];
    }
#pragma unroll
    for (int j = 0; j < 4; ++j) t2[j] += __shfl_xor(u2[j], 2);
    float t3[2], u3[2];
#pragma unroll
    for (int j = 0; j < 2; ++j) {
        t3[j] = b2 ? t2[j + 2] : t2[j];
        u3[j] = b2 ? t2[j] : t2[j + 2];
    }
#pragma unroll
    for (int j = 0; j < 2; ++j) t3[j] += __shfl_xor(u3[j], 4);

    const int c0 = (b0 ? 8 : 0) + (b1 ? 4 : 0) + (b2 ? 2 : 0);
    const float inv = 1.0f / (den + 1e-16f);
    const int c = cb + c0;
    const float o0 = elu_f(t3[0] * inv + bias1[c]);
    const float o1 = elu_f(t3[1] * inv + bias1[c + 1]);
    *(float2*)&h1[(size_t)d * 128 + c] = make_float2(o0, o1);
}

// ---------------- GEMM2: xl2 = h1@wl2+bl2, xr2 = h1@wr2+br2 ([N,128]x[128,16]) -
__global__ __launch_bounds__(256) void k_gemm2(
    const float* __restrict__ h1, const float* __restrict__ wl,
    const float* __restrict__ bl, const float* __restrict__ wr,
    const float* __restrict__ br, float* __restrict__ xl2, float* __restrict__ xr2)
{
    __shared__ float xs[32 * 132];
    const int tid = threadIdx.x;
    const int n0  = blockIdx.x * 32;
    const int nrem = min(32, NN - n0);

    for (int i = tid; i < nrem * 128; i += 256) {
        int row = i >> 7, col = i & 127;
        xs[row * 132 + col] = h1[(size_t)(n0 + row) * 128 + col];
    }
    __syncthreads();

    const int r  = tid >> 3;        // 0..31
    const int c0 = (tid & 7) * 4;   // 0..28
    const float* w; const float* b; float* outp; int c;
    if (c0 < 16) { w = wl; b = bl; outp = xl2; c = c0; }
    else         { w = wr; b = br; outp = xr2; c = c0 - 16; }

    float4 acc = make_float4(0.f, 0.f, 0.f, 0.f);
    for (int k4 = 0; k4 < 32; ++k4) {
        const float4 w0 = *(const float4*)&w[(k4*4+0)*16 + c];
        const float4 w1 = *(const float4*)&w[(k4*4+1)*16 + c];
        const float4 w2 = *(const float4*)&w[(k4*4+2)*16 + c];
        const float4 w3 = *(const float4*)&w[(k4*4+3)*16 + c];
        const float4 xv = *(const float4*)&xs[r * 132 + k4 * 4];
        acc.x += xv.x*w0.x + xv.y*w1.x + xv.z*w2.x + xv.w*w3.x;
        acc.y += xv.x*w0.y + xv.y*w1.y + xv.z*w2.y + xv.w*w3.y;
        acc.z += xv.x*w0.z + xv.y*w1.z + xv.z*w2.z + xv.w*w3.z;
        acc.w += xv.x*w0.w + xv.y*w1.w + xv.z*w2.w + xv.w*w3.w;
    }
    if (r < nrem) {
        const float4 bv = *(const float4*)&b[c];
        float4 o = make_float4(acc.x + bv.x, acc.y + bv.y, acc.z + bv.z, acc.w + bv.w);
        *(float4*)&outp[(size_t)(n0 + r) * 16 + c] = o;
    }
}

// ---------------- conv2 aggregation: one wave per dst, h2 output ---------------
__global__ __launch_bounds__(256) void k_conv2_agg(
    const float* __restrict__ xl2, const float* __restrict__ xr2,
    const float* __restrict__ att, const float* __restrict__ bias2,
    const int* __restrict__ rowp, const int* __restrict__ slist,
    float* __restrict__ h2)
{
    const int d = (blockIdx.x * 256 + threadIdx.x) >> 6;   // wave id = dst
    if (d >= NN) return;
    const int lane = threadIdx.x & 63;
    const int eq = lane >> 2, c4 = lane & 3;

    const float4 xr = *(const float4*)&xr2[(size_t)d * 16 + c4 * 4];
    const float4 at = *(const float4*)&att[c4 * 4];
    const int beg = rowp[d], end = rowp[d + 1];

    float den = 0.f;
    float4 acc = make_float4(0.f, 0.f, 0.f, 0.f);

    for (int base = beg; base < end; base += 64) {
        const int nb = min(64, end - base);
        int sv = (lane < nb) ? slist[base + lane] : 0;
        for (int c16 = 0; c16 * 16 < nb; ++c16) {
            const int idx = c16 * 16 + eq;
            const int src = __shfl(sv, idx & 63);
            if (idx < nb) {
                const float4 v = *(const float4*)&xl2[(size_t)src * 16 + c4 * 4];
                float pp = at.x * lrelu_f(v.x + xr.x)
                         + at.y * lrelu_f(v.y + xr.y)
                         + at.z * lrelu_f(v.z + xr.z)
                         + at.w * lrelu_f(v.w + xr.w);
                pp += __shfl_xor(pp, 1);   // reduce over c4 quad (uniform within)
                pp += __shfl_xor(pp, 2);
                const float w = __expf(fminf(pp, 80.f));
                den += w;
                acc.x += w * v.x;
                acc.y += w * v.y;
                acc.z += w * v.z;
                acc.w += w * v.w;
            }
        }
    }
    // merge the 16 edge streams (lanes with same c4)
#pragma unroll
    for (int ofs = 4; ofs < 64; ofs <<= 1) {
        den   += __shfl_xor(den, ofs);
        acc.x += __shfl_xor(acc.x, ofs);
        acc.y += __shfl_xor(acc.y, ofs);
        acc.z += __shfl_xor(acc.z, ofs);
        acc.w += __shfl_xor(acc.w, ofs);
    }
    if (eq == 0) {
        const float inv = 1.0f / (den + 1e-16f);
        const float4 bv = *(const float4*)&bias2[c4 * 4];
        float4 o;
        o.x = elu_f(acc.x * inv + bv.x);
        o.y = elu_f(acc.y * inv + bv.y);
        o.z = elu_f(acc.z * inv + bv.z);
        o.w = elu_f(acc.w * inv + bv.w);
        *(float4*)&h2[(size_t)d * 16 + c4 * 4] = o;   // lanes 0..3: 64 B row
    }
}

// ---------------- mean pool: one block per graph, zero atomics -----------------
__global__ __launch_bounds__(256) void k_pool(
    const float* __restrict__ h2, const int* __restrict__ batch,
    float* __restrict__ pooled, float* __restrict__ cnt)
{
    __shared__ int se[2];
    __shared__ float sm[256];
    const int b = blockIdx.x, tid = threadIdx.x;
    if (tid < 2) {
        int key = b + tid, lo = 0, hi = NN;
        while (lo < hi) {
            int mid = (lo + hi) >> 1;
            if (batch[mid] < key) lo = mid + 1; else hi = mid;
        }
        se[tid] = lo;
    }
    __syncthreads();
    const int s = se[0], e = se[1];
    const int c = tid & 15, slot = tid >> 4;
    float acc = 0.f;
    for (int n = s + slot; n < e; n += 16) acc += h2[(size_t)n * 16 + c];
    sm[tid] = acc;
    __syncthreads();
    for (int ofs = 128; ofs >= 16; ofs >>= 1) {
        if (tid < ofs) sm[tid] += sm[tid + ofs];
        __syncthreads();
    }
    if (tid < 16) pooled[b * 16 + tid] = sm[tid];
    if (tid == 16) cnt[b] = (float)(e - s);
}

// ---------------- MLP head: one thread per graph -------------------------------
__global__ __launch_bounds__(256) void k_mlp(
    const float* __restrict__ pooled, const float* __restrict__ cnt,
    const float* __restrict__ w1, const float* __restrict__ b1,
    const float* __restrict__ w2, const float* __restrict__ b2,
    const float* __restrict__ w3, const float* __restrict__ b3,
    float* __restrict__ out)
{
    __shared__ float w1s[16*32], w2s[32*16], w3s[16*32], b1s[32], b2s[16], b3s[32];
    const int tid = threadIdx.x;
    for (int i = tid; i < 512; i += 256) { w1s[i] = w1[i]; w2s[i] = w2[i]; w3s[i] = w3[i]; }
    if (tid < 32) b1s[tid] = b1[tid];
    if (tid < 16) b2s[tid] = b2[tid];
    if (tid < 32) b3s[tid] = b3[tid];
    __syncthreads();

    const int g = tid;  // graph id, 0..255
    const float inv = 1.0f / fmaxf(cnt[g], 1.0f);
    float hb[16];
#pragma unroll
    for (int k = 0; k < 16; ++k) hb[k] = pooled[g * 16 + k] * inv;

    float t1[32];
#pragma unroll
    for (int j = 0; j < 32; ++j) t1[j] = b1s[j];
    for (int k = 0; k < 16; ++k)
#pragma unroll
        for (int j = 0; j < 32; ++j) t1[j] += hb[k] * w1s[k * 32 + j];
#pragma unroll
    for (int j = 0; j < 32; ++j) t1[j] = elu_f(t1[j]);

    float t2[16];
#pragma unroll
    for (int j = 0; j < 16; ++j) t2[j] = b2s[j];
    for (int k = 0; k < 32; ++k)
#pragma unroll
        for (int j = 0; j < 16; ++j) t2[j] += t1[k] * w2s[k * 16 + j];
#pragma unroll
    for (int j = 0; j < 16; ++j) t2[j] = elu_f(t2[j]);

#pragma unroll
    for (int j = 0; j < 32; ++j) {
        float o = b3s[j];
        for (int k = 0; k < 16; ++k) o += t2[k] * w3s[k * 32 + j];
        out[g * 32 + j] = o;
    }
}

// ---------------- launch -------------------------------------------------------
extern "C" void kernel_launch(void* const* d_in, const int* in_sizes, int n_in,
                              void* d_out, int out_size, void* d_ws, size_t ws_size,
                              hipStream_t stream)
{
    const float* x     = (const float*)d_in[0];
    const int*   ei    = (const int*)d_in[1];
    const int*   batch = (const int*)d_in[2];
    const float* wl1   = (const float*)d_in[3];
    const float* bl1   = (const float*)d_in[4];
    const float* wr1   = (const float*)d_in[5];
    const float* br1   = (const float*)d_in[6];
    const float* att1  = (const float*)d_in[7];
    const float* bias1 = (const float*)d_in[8];
    const float* wl2   = (const float*)d_in[9];
    const float* bl2   = (const float*)d_in[10];
    const float* wr2   = (const float*)d_in[11];
    const float* br2   = (const float*)d_in[12];
    const float* att2  = (const float*)d_in[13];
    const float* bias2 = (const float*)d_in[14];
    const float* wm1   = (const float*)d_in[15];
    const float* bm1   = (const float*)d_in[16];
    const float* wm2   = (const float*)d_in[17];
    const float* bm2   = (const float*)d_in[18];
    const float* wm3   = (const float*)d_in[19];
    const float* bm3   = (const float*)d_in[20];
    float* out = (float*)d_out;

    char* base = (char*)d_ws;
    size_t off = 0;
    auto alloc = [&](size_t bytes) -> void* {
        void* p = base + off;
        off += (bytes + 255) & ~(size_t)255;
        return p;
    };
    float* xl1   = (float*)alloc((size_t)NN * 128 * 4);
    float* xr1   = (float*)alloc((size_t)NN * 128 * 4);
    float* h1    = (float*)alloc((size_t)NN * 128 * 4);
    int*   slist = (int*)  alloc((size_t)EP * 4);
    unsigned long long* bb = (unsigned long long*)alloc((size_t)NE * 8);
    int*   rowp  = (int*)  alloc((size_t)(NN + 1) * 4);
    int*   bcnt  = (int*)  alloc((size_t)NBKT * 4);
    int*   bstart= (int*)  alloc((size_t)(NBKT + 1) * 4);
    int*   bcursor=(int*)  alloc((size_t)NBKT * 4);
    float* pooled= (float*)alloc((size_t)NB * 16 * 4);
    float* cnt   = (float*)alloc((size_t)NB * 4);
    // conv2 tensors reuse xl1's region (dead after k_conv1_agg)
    float* xl2 = xl1;
    float* xr2 = xl1 + (size_t)NN * 16;
    float* h2  = xl1 + (size_t)NN * 32;

    hipMemsetAsync(bcnt, 0, (size_t)NBKT * 4, stream);
    k_gemm1<<<(NN + 31) / 32, 256, 0, stream>>>(x, wl1, bl1, wr1, br1, xl1, xr1);
    k_bhist<<<EBLK, 256, 0, stream>>>(ei, bcnt);
    k_bscan<<<1, 512, 0, stream>>>(bcnt, bstart, bcursor);
    k_bucket<<<EBLK, 256, 0, stream>>>(ei, bcursor, bb);
    k_bfinal<<<NBKT, 256, 0, stream>>>(bb, bstart, rowp, slist);
    k_conv1_agg<<<(NN * 64) / 256, 256, 0, stream>>>(xl1, xr1, att1, bias1, rowp, slist, h1);
    k_gemm2<<<(NN + 31) / 32, 256, 0, stream>>>(h1, wl2, bl2, wr2, br2, xl2, xr2);
    k_conv2_agg<<<(NN * 64) / 256, 256, 0, stream>>>(xl2, xr2, att2, bias2, rowp, slist, h2);
    k_pool<<<NB, 256, 0, stream>>>(h2, batch, pooled, cnt);
    k_mlp<<<1, 256, 0, stream>>>(pooled, cnt, wm1, bm1, wm2, bm2, wm3, bm3, out);
}

// Round 7
// 347.729 us; speedup vs baseline: 2.9315x; 1.1389x over previous
//
#include <hip/hip_runtime.h>
#include <hip/hip_bf16.h>
#include <hip/hip_fp16.h>
#include <math.h>

#define NN   50000
#define NE   1600000
#define EP   (NE + NN)       // edges + self loops = 1,650,000
#define NB   256
#define BK_SH 7              // 128 dsts per bucket
#define NBKT ((NN + 127) >> BK_SH)   // 391
#define ET   32              // edges per thread in bucket kernels
#define EB   (256 * ET)      // 8192 edges per block
#define EBLK ((NE + EB - 1) / EB)    // 196 blocks

__device__ __forceinline__ float elu_f(float x)   { return x > 0.0f ? x : expm1f(x); }
// leaky_relu(x, 0.2) == max(x, 0.2x) since 0.2 > 0
__device__ __forceinline__ float lrelu_f(float x) { return fmaxf(x, 0.2f * x); }

// ---------------- GEMM1: xl1(half) = x@wl1+bl1, xr1(f32) = x@wr1+br1 -----------
__global__ __launch_bounds__(256) void k_gemm1(
    const float* __restrict__ x, const float* __restrict__ wl,
    const float* __restrict__ bl, const float* __restrict__ wr,
    const float* __restrict__ br, __half* __restrict__ xl1, float* __restrict__ xr1)
{
    __shared__ float xs[32 * 64];
    const int tid = threadIdx.x;
    const int n0  = blockIdx.x * 32;
    const int nrem = min(32, NN - n0);

    const float4* xg = (const float4*)(x + (size_t)n0 * 64);
    float4* xs4 = (float4*)xs;
    const int lim4 = nrem * 16;
    for (int i = tid; i < lim4; i += 256) xs4[i] = xg[i];
    __syncthreads();

    const int g  = tid >> 6;        // 0..3 -> rows 8g..8g+7
    const int c0 = (tid & 63) * 4;  // 0..252
    const bool isl = (c0 < 128);
    const float* w  = isl ? wl : wr;
    const float* b  = isl ? bl : br;
    const int    cw = isl ? c0 : (c0 - 128);

    float4 acc[8];
#pragma unroll
    for (int r = 0; r < 8; ++r) acc[r] = make_float4(0.f, 0.f, 0.f, 0.f);

    for (int k4 = 0; k4 < 16; ++k4) {
        const float4 w0 = *(const float4*)&w[(k4*4+0)*128 + cw];
        const float4 w1 = *(const float4*)&w[(k4*4+1)*128 + cw];
        const float4 w2 = *(const float4*)&w[(k4*4+2)*128 + cw];
        const float4 w3 = *(const float4*)&w[(k4*4+3)*128 + cw];
#pragma unroll
        for (int r = 0; r < 8; ++r) {
            const float4 xv = xs4[(g*8+r)*16 + k4];
            acc[r].x += xv.x*w0.x + xv.y*w1.x + xv.z*w2.x + xv.w*w3.x;
            acc[r].y += xv.x*w0.y + xv.y*w1.y + xv.z*w2.y + xv.w*w3.y;
            acc[r].z += xv.x*w0.z + xv.y*w1.z + xv.z*w2.z + xv.w*w3.z;
            acc[r].w += xv.x*w0.w + xv.y*w1.w + xv.z*w2.w + xv.w*w3.w;
        }
    }
    const float4 bv = *(const float4*)&b[cw];
#pragma unroll
    for (int r = 0; r < 8; ++r) {
        const int row = g*8 + r;
        if (row < nrem) {
            float4 o = make_float4(acc[r].x + bv.x, acc[r].y + bv.y,
                                   acc[r].z + bv.z, acc[r].w + bv.w);
            if (isl) {
                __half2* dst = (__half2*)&xl1[(size_t)(n0 + row) * 128 + cw];
                dst[0] = __floats2half2_rn(o.x, o.y);
                dst[1] = __floats2half2_rn(o.z, o.w);
            } else {
                *(float4*)&xr1[(size_t)(n0 + row) * 128 + cw] = o;
            }
        }
    }
}

// ---------------- CSR build via two-pass bucket sort ---------------------------
// bhist: LDS-aggregated histogram of edge dst buckets -> bcnt[NBKT]
__global__ __launch_bounds__(256) void k_bhist(const int* __restrict__ ei,
                                               int* __restrict__ bcnt)
{
    __shared__ int lh[NBKT];
    const int tid = threadIdx.x;
    for (int i = tid; i < NBKT; i += 256) lh[i] = 0;
    __syncthreads();
    const int t = blockIdx.x * 256 + tid;
    if (t * ET < NE) {
        const int4* dp = (const int4*)&ei[NE + t * ET];
#pragma unroll
        for (int q = 0; q < ET / 4; ++q) {
            int4 d = dp[q];
            atomicAdd(&lh[d.x >> BK_SH], 1);
            atomicAdd(&lh[d.y >> BK_SH], 1);
            atomicAdd(&lh[d.z >> BK_SH], 1);
            atomicAdd(&lh[d.w >> BK_SH], 1);
        }
    }
    __syncthreads();
    for (int i = tid; i < NBKT; i += 256) {
        int v = lh[i];
        if (v > 0) atomicAdd(&bcnt[i], v);
    }
}

// bscan: one block (512 thr) exclusive-scans bcnt -> bstart, bcursor
__global__ __launch_bounds__(512) void k_bscan(const int* __restrict__ bcnt,
                                               int* __restrict__ bstart,
                                               int* __restrict__ bcursor)
{
    __shared__ int sm[512];
    const int t = threadIdx.x;
    const int c = (t < NBKT) ? bcnt[t] : 0;
    sm[t] = c;
    __syncthreads();
    for (int ofs = 1; ofs < 512; ofs <<= 1) {
        int v = (t >= ofs) ? sm[t - ofs] : 0;
        __syncthreads();
        sm[t] += v;
        __syncthreads();
    }
    if (t < NBKT) {
        int ex = sm[t] - c;
        bstart[t] = ex;
        bcursor[t] = ex;
    }
    if (t == NBKT) bstart[NBKT] = NE;   // NBKT < 512
}

// bucket: scatter packed u32 ((d&127)<<17 | src) into bucket regions.
// src < 50000 < 2^17, dloc < 128 -> 24 bits. Per-block LDS histogram + one
// reserving global atomic per bucket -> contiguous per-block runs.
__global__ __launch_bounds__(256) void k_bucket(const int* __restrict__ ei,
                                                int* __restrict__ bcursor,
                                                unsigned int* __restrict__ bb)
{
    __shared__ int lh[NBKT];
    __shared__ int cur[NBKT];
    const int tid = threadIdx.x;
    for (int i = tid; i < NBKT; i += 256) lh[i] = 0;
    __syncthreads();

    const int t = blockIdx.x * 256 + tid;
    const bool act = (t * ET < NE);
    int4 dreg[ET / 4];
    if (act) {
        const int4* dp = (const int4*)&ei[NE + t * ET];
#pragma unroll
        for (int q = 0; q < ET / 4; ++q) {
            dreg[q] = dp[q];
            atomicAdd(&lh[dreg[q].x >> BK_SH], 1);
            atomicAdd(&lh[dreg[q].y >> BK_SH], 1);
            atomicAdd(&lh[dreg[q].z >> BK_SH], 1);
            atomicAdd(&lh[dreg[q].w >> BK_SH], 1);
        }
    }
    __syncthreads();
    for (int i = tid; i < NBKT; i += 256) {
        int h = lh[i];
        if (h > 0) cur[i] = atomicAdd(&bcursor[i], h);
    }
    __syncthreads();
    if (act) {
        const int4* sp = (const int4*)&ei[t * ET];
#pragma unroll
        for (int q = 0; q < ET / 4; ++q) {
            int4 s = sp[q];
            int4 d = dreg[q];
            int p;
            p = atomicAdd(&cur[d.x >> BK_SH], 1);
            bb[p] = ((unsigned)(d.x & 127) << 17) | (unsigned)s.x;
            p = atomicAdd(&cur[d.y >> BK_SH], 1);
            bb[p] = ((unsigned)(d.y & 127) << 17) | (unsigned)s.y;
            p = atomicAdd(&cur[d.z >> BK_SH], 1);
            bb[p] = ((unsigned)(d.z & 127) << 17) | (unsigned)s.z;
            p = atomicAdd(&cur[d.w >> BK_SH], 1);
            bb[p] = ((unsigned)(d.w & 127) << 17) | (unsigned)s.w;
        }
    }
}

// bfinal: one block per bucket. Per-dst LDS count (+1 self-loop) -> scan ->
// rowp; then scatter slist within the bucket's contiguous output range.
__global__ __launch_bounds__(256) void k_bfinal(
    const unsigned int* __restrict__ bb, const int* __restrict__ bstart,
    int* __restrict__ rowp, int* __restrict__ slist)
{
    __shared__ int cnt[128], cur[128];
    const int b = blockIdx.x, tid = threadIdx.x;
    const int db0 = b << BK_SH;
    const int dn  = min(128, NN - db0);
    const int ebeg = bstart[b], eend = bstart[b + 1];
    const int out0 = ebeg + db0;

    int c0 = 0;
    if (tid < 128) {
        c0 = (tid < dn) ? 1 : 0;       // self-loop
        cnt[tid] = c0;
    }
    __syncthreads();
    for (int i = ebeg + tid; i < eend; i += 256) {
        unsigned u = bb[i];
        atomicAdd(&cnt[u >> 17], 1);
    }
    __syncthreads();
    if (tid < 128) c0 = cnt[tid];      // per-dst total (incl. self-loop)
    // inclusive scan of cnt[128]
    for (int ofs = 1; ofs < 128; ofs <<= 1) {
        int v = 0;
        if (tid < 128 && tid >= ofs) v = cnt[tid - ofs];
        __syncthreads();
        if (tid < 128) cnt[tid] += v;
        __syncthreads();
    }
    if (tid < 128) {
        int ex = cnt[tid] - c0;        // exclusive
        cur[tid] = ex + 1;             // slot 0 reserved for self-loop
        if (tid < dn) {
            rowp[db0 + tid] = out0 + ex;
            slist[out0 + ex] = db0 + tid;   // self-loop
        }
    }
    if (b == 0 && tid == 0) rowp[NN] = EP;
    __syncthreads();
    for (int i = ebeg + tid; i < eend; i += 256) {
        unsigned u = bb[i];
        int p = atomicAdd(&cur[u >> 17], 1);
        slist[out0 + p] = (int)(u & 0x1FFFFu);
    }
}

// ---------------- conv1 aggregation: one wave per dst --------------------------
// lane = (h = lane>>3, e = lane&7): lane owns head h, edge-slot e -> 8 edges
// per iteration; gathered xl1 rows are fp16 (32 B/head-row, 2x16B loads).
__global__ __launch_bounds__(256) void k_conv1_agg(
    const __half* __restrict__ xl1, const float* __restrict__ xr1,
    const float* __restrict__ att, const float* __restrict__ bias1,
    const int* __restrict__ rowp, const int* __restrict__ slist,
    float* __restrict__ h1)
{
    const int d = (blockIdx.x * 256 + threadIdx.x) >> 6;   // wave id = dst
    if (d >= NN) return;
    const int lane = threadIdx.x & 63;
    const int h = lane >> 3, e = lane & 7;
    const int cb = h * 16;

    float xrv[16], atv[16];
    {
        const float4* xrp = (const float4*)&xr1[(size_t)d * 128 + cb];
        const float4* atp = (const float4*)&att[cb];
#pragma unroll
        for (int q = 0; q < 4; ++q) {
            float4 a4 = xrp[q];
            xrv[q*4+0] = a4.x; xrv[q*4+1] = a4.y; xrv[q*4+2] = a4.z; xrv[q*4+3] = a4.w;
            float4 b4 = atp[q];
            atv[q*4+0] = b4.x; atv[q*4+1] = b4.y; atv[q*4+2] = b4.z; atv[q*4+3] = b4.w;
        }
    }

    const int beg = rowp[d], end = rowp[d + 1];

    float den = 0.f;
    float a[16];
#pragma unroll
    for (int c = 0; c < 16; ++c) a[c] = 0.f;

    for (int base = beg; base < end; base += 64) {
        const int nb = min(64, end - base);
        int sv = (lane < nb) ? slist[base + lane] : 0;
        for (int c8 = 0; c8 * 8 < nb; ++c8) {
            const int idx = c8 * 8 + e;
            const int src = __shfl(sv, idx);      // idx <= 63 always
            if (idx < nb) {
                const float4* vp = (const float4*)(xl1 + (size_t)src * 128 + cb);
                const float4 r0 = vp[0], r1 = vp[1];   // 16 halves
                float v[16];
                {
                    const __half2* hh = (const __half2*)&r0;
#pragma unroll
                    for (int q = 0; q < 4; ++q) {
                        float2 f = __half22float2(hh[q]);
                        v[2*q] = f.x; v[2*q+1] = f.y;
                    }
                    const __half2* hg = (const __half2*)&r1;
#pragma unroll
                    for (int q = 0; q < 4; ++q) {
                        float2 f = __half22float2(hg[q]);
                        v[8+2*q] = f.x; v[9+2*q] = f.y;
                    }
                }
                float s = 0.f;
#pragma unroll
                for (int c = 0; c < 16; ++c) s += atv[c] * lrelu_f(v[c] + xrv[c]);
                const float w = __expf(fminf(s, 80.f));
                den += w;
#pragma unroll
                for (int c = 0; c < 16; ++c) a[c] += w * v[c];
            }
        }
    }

    // sum den over the 8 e-lanes of this head
    den += __shfl_xor(den, 1);
    den += __shfl_xor(den, 2);
    den += __shfl_xor(den, 4);

    // reduce-scatter a[16] over e-lanes: each level halves the channel set
    const bool b0 = (e & 1), b1 = (e & 2), b2 = (e & 4);
    float t1[8], u1[8];
#pragma unroll
    for (int j = 0; j < 8; ++j) {
        t1[j] = b0 ? a[j + 8] : a[j];
        u1[j] = b0 ? a[j] : a[j + 8];
    }
#pragma unroll
    for (int j = 0; j < 8; ++j) t1[j] += __shfl_xor(u1[j], 1);
    float t2[4], u2[4];
#pragma unroll
    for (int j = 0; j < 4; ++j) {
        t2[j] = b1 ? t1[j + 4] : t1[j];
        u2[j] = b1 ? t1[j] : t1[j + 4];
    }
#pragma unroll
    for (int j = 0; j < 4; ++j) t2[j] += __shfl_xor(u2[j], 2);
    float t3[2], u3[2];
#pragma unroll
    for (int j = 0; j < 2; ++j) {
        t3[j] = b2 ? t2[j + 2] : t2[j];
        u3[j] = b2 ? t2[j] : t2[j + 2];
    }
#pragma unroll
    for (int j = 0; j < 2; ++j) t3[j] += __shfl_xor(u3[j], 4);

    const int c0 = (b0 ? 8 : 0) + (b1 ? 4 : 0) + (b2 ? 2 : 0);
    const float inv = 1.0f / (den + 1e-16f);
    const int c = cb + c0;
    const float o0 = elu_f(t3[0] * inv + bias1[c]);
    const float o1 = elu_f(t3[1] * inv + bias1[c + 1]);
    *(float2*)&h1[(size_t)d * 128 + c] = make_float2(o0, o1);
}

// ---------------- GEMM2: xl2(half) = h1@wl2+bl2, xr2(f32) = h1@wr2+br2 ---------
__global__ __launch_bounds__(256) void k_gemm2(
    const float* __restrict__ h1, const float* __restrict__ wl,
    const float* __restrict__ bl, const float* __restrict__ wr,
    const float* __restrict__ br, __half* __restrict__ xl2, float* __restrict__ xr2)
{
    __shared__ float xs[32 * 132];
    const int tid = threadIdx.x;
    const int n0  = blockIdx.x * 32;
    const int nrem = min(32, NN - n0);

    for (int i = tid; i < nrem * 128; i += 256) {
        int row = i >> 7, col = i & 127;
        xs[row * 132 + col] = h1[(size_t)(n0 + row) * 128 + col];
    }
    __syncthreads();

    const int r  = tid >> 3;        // 0..31
    const int c0 = (tid & 7) * 4;   // 0..28
    const bool isl = (c0 < 16);
    const float* w = isl ? wl : wr;
    const float* b = isl ? bl : br;
    const int    c = isl ? c0 : (c0 - 16);

    float4 acc = make_float4(0.f, 0.f, 0.f, 0.f);
    for (int k4 = 0; k4 < 32; ++k4) {
        const float4 w0 = *(const float4*)&w[(k4*4+0)*16 + c];
        const float4 w1 = *(const float4*)&w[(k4*4+1)*16 + c];
        const float4 w2 = *(const float4*)&w[(k4*4+2)*16 + c];
        const float4 w3 = *(const float4*)&w[(k4*4+3)*16 + c];
        const float4 xv = *(const float4*)&xs[r * 132 + k4 * 4];
        acc.x += xv.x*w0.x + xv.y*w1.x + xv.z*w2.x + xv.w*w3.x;
        acc.y += xv.x*w0.y + xv.y*w1.y + xv.z*w2.y + xv.w*w3.y;
        acc.z += xv.x*w0.z + xv.y*w1.z + xv.z*w2.z + xv.w*w3.z;
        acc.w += xv.x*w0.w + xv.y*w1.w + xv.z*w2.w + xv.w*w3.w;
    }
    if (r < nrem) {
        const float4 bv = *(const float4*)&b[c];
        float4 o = make_float4(acc.x + bv.x, acc.y + bv.y, acc.z + bv.z, acc.w + bv.w);
        if (isl) {
            __half2* dst = (__half2*)&xl2[(size_t)(n0 + r) * 16 + c];
            dst[0] = __floats2half2_rn(o.x, o.y);
            dst[1] = __floats2half2_rn(o.z, o.w);
        } else {
            *(float4*)&xr2[(size_t)(n0 + r) * 16 + c] = o;
        }
    }
}

// ---------------- conv2 aggregation: one wave per dst, h2 output ---------------
__global__ __launch_bounds__(256) void k_conv2_agg(
    const __half* __restrict__ xl2, const float* __restrict__ xr2,
    const float* __restrict__ att, const float* __restrict__ bias2,
    const int* __restrict__ rowp, const int* __restrict__ slist,
    float* __restrict__ h2)
{
    const int d = (blockIdx.x * 256 + threadIdx.x) >> 6;   // wave id = dst
    if (d >= NN) return;
    const int lane = threadIdx.x & 63;
    const int eq = lane >> 2, c4 = lane & 3;

    const float4 xr = *(const float4*)&xr2[(size_t)d * 16 + c4 * 4];
    const float4 at = *(const float4*)&att[c4 * 4];
    const int beg = rowp[d], end = rowp[d + 1];

    float den = 0.f;
    float4 acc = make_float4(0.f, 0.f, 0.f, 0.f);

    for (int base = beg; base < end; base += 64) {
        const int nb = min(64, end - base);
        int sv = (lane < nb) ? slist[base + lane] : 0;
        for (int c16 = 0; c16 * 16 < nb; ++c16) {
            const int idx = c16 * 16 + eq;
            const int src = __shfl(sv, idx & 63);
            if (idx < nb) {
                const __half2* hp = (const __half2*)(xl2 + (size_t)src * 16 + c4 * 4);
                const float2 f0 = __half22float2(hp[0]);
                const float2 f1 = __half22float2(hp[1]);
                float pp = at.x * lrelu_f(f0.x + xr.x)
                         + at.y * lrelu_f(f0.y + xr.y)
                         + at.z * lrelu_f(f1.x + xr.z)
                         + at.w * lrelu_f(f1.y + xr.w);
                pp += __shfl_xor(pp, 1);   // reduce over c4 quad (uniform within)
                pp += __shfl_xor(pp, 2);
                const float w = __expf(fminf(pp, 80.f));
                den += w;
                acc.x += w * f0.x;
                acc.y += w * f0.y;
                acc.z += w * f1.x;
                acc.w += w * f1.y;
            }
        }
    }
    // merge the 16 edge streams (lanes with same c4)
#pragma unroll
    for (int ofs = 4; ofs < 64; ofs <<= 1) {
        den   += __shfl_xor(den, ofs);
        acc.x += __shfl_xor(acc.x, ofs);
        acc.y += __shfl_xor(acc.y, ofs);
        acc.z += __shfl_xor(acc.z, ofs);
        acc.w += __shfl_xor(acc.w, ofs);
    }
    if (eq == 0) {
        const float inv = 1.0f / (den + 1e-16f);
        const float4 bv = *(const float4*)&bias2[c4 * 4];
        float4 o;
        o.x = elu_f(acc.x * inv + bv.x);
        o.y = elu_f(acc.y * inv + bv.y);
        o.z = elu_f(acc.z * inv + bv.z);
        o.w = elu_f(acc.w * inv + bv.w);
        *(float4*)&h2[(size_t)d * 16 + c4 * 4] = o;   // lanes 0..3: 64 B row
    }
}

// ---------------- mean pool: one block per graph, zero atomics -----------------
__global__ __launch_bounds__(256) void k_pool(
    const float* __restrict__ h2, const int* __restrict__ batch,
    float* __restrict__ pooled, float* __restrict__ cnt)
{
    __shared__ int se[2];
    __shared__ float sm[256];
    const int b = blockIdx.x, tid = threadIdx.x;
    if (tid < 2) {
        int key = b + tid, lo = 0, hi = NN;
        while (lo < hi) {
            int mid = (lo + hi) >> 1;
            if (batch[mid] < key) lo = mid + 1; else hi = mid;
        }
        se[tid] = lo;
    }
    __syncthreads();
    const int s = se[0], e = se[1];
    const int c = tid & 15, slot = tid >> 4;
    float acc = 0.f;
    for (int n = s + slot; n < e; n += 16) acc += h2[(size_t)n * 16 + c];
    sm[tid] = acc;
    __syncthreads();
    for (int ofs = 128; ofs >= 16; ofs >>= 1) {
        if (tid < ofs) sm[tid] += sm[tid + ofs];
        __syncthreads();
    }
    if (tid < 16) pooled[b * 16 + tid] = sm[tid];
    if (tid == 16) cnt[b] = (float)(e - s);
}

// ---------------- MLP head: one thread per graph -------------------------------
__global__ __launch_bounds__(256) void k_mlp(
    const float* __restrict__ pooled, const float* __restrict__ cnt,
    const float* __restrict__ w1, const float* __restrict__ b1,
    const float* __restrict__ w2, const float* __restrict__ b2,
    const float* __restrict__ w3, const float* __restrict__ b3,
    float* __restrict__ out)
{
    __shared__ float w1s[16*32], w2s[32*16], w3s[16*32], b1s[32], b2s[16], b3s[32];
    const int tid = threadIdx.x;
    for (int i = tid; i < 512; i += 256) { w1s[i] = w1[i]; w2s[i] = w2[i]; w3s[i] = w3[i]; }
    if (tid < 32) b1s[tid] = b1[tid];
    if (tid < 16) b2s[tid] = b2[tid];
    if (tid < 32) b3s[tid] = b3[tid];
    __syncthreads();

    const int g = tid;  // graph id, 0..255
    const float inv = 1.0f / fmaxf(cnt[g], 1.0f);
    float hb[16];
#pragma unroll
    for (int k = 0; k < 16; ++k) hb[k] = pooled[g * 16 + k] * inv;

    float t1[32];
#pragma unroll
    for (int j = 0; j < 32; ++j) t1[j] = b1s[j];
    for (int k = 0; k < 16; ++k)
#pragma unroll
        for (int j = 0; j < 32; ++j) t1[j] += hb[k] * w1s[k * 32 + j];
#pragma unroll
    for (int j = 0; j < 32; ++j) t1[j] = elu_f(t1[j]);

    float t2[16];
#pragma unroll
    for (int j = 0; j < 16; ++j) t2[j] = b2s[j];
    for (int k = 0; k < 32; ++k)
#pragma unroll
        for (int j = 0; j < 16; ++j) t2[j] += t1[k] * w2s[k * 16 + j];
#pragma unroll
    for (int j = 0; j < 16; ++j) t2[j] = elu_f(t2[j]);

#pragma unroll
    for (int j = 0; j < 32; ++j) {
        float o = b3s[j];
        for (int k = 0; k < 16; ++k) o += t2[k] * w3s[k * 32 + j];
        out[g * 32 + j] = o;
    }
}

// ---------------- launch -------------------------------------------------------
extern "C" void kernel_launch(void* const* d_in, const int* in_sizes, int n_in,
                              void* d_out, int out_size, void* d_ws, size_t ws_size,
                              hipStream_t stream)
{
    const float* x     = (const float*)d_in[0];
    const int*   ei    = (const int*)d_in[1];
    const int*   batch = (const int*)d_in[2];
    const float* wl1   = (const float*)d_in[3];
    const float* bl1   = (const float*)d_in[4];
    const float* wr1   = (const float*)d_in[5];
    const float* br1   = (const float*)d_in[6];
    const float* att1  = (const float*)d_in[7];
    const float* bias1 = (const float*)d_in[8];
    const float* wl2   = (const float*)d_in[9];
    const float* bl2   = (const float*)d_in[10];
    const float* wr2   = (const float*)d_in[11];
    const float* br2   = (const float*)d_in[12];
    const float* att2  = (const float*)d_in[13];
    const float* bias2 = (const float*)d_in[14];
    const float* wm1   = (const float*)d_in[15];
    const float* bm1   = (const float*)d_in[16];
    const float* wm2   = (const float*)d_in[17];
    const float* bm2   = (const float*)d_in[18];
    const float* wm3   = (const float*)d_in[19];
    const float* bm3   = (const float*)d_in[20];
    float* out = (float*)d_out;

    char* base = (char*)d_ws;
    size_t off = 0;
    auto alloc = [&](size_t bytes) -> void* {
        void* p = base + off;
        off += (bytes + 255) & ~(size_t)255;
        return p;
    };
    __half* xl1  = (__half*)alloc((size_t)NN * 128 * 2);
    float* xr1   = (float*)alloc((size_t)NN * 128 * 4);
    float* h1    = (float*)alloc((size_t)NN * 128 * 4);
    int*   slist = (int*)  alloc((size_t)EP * 4);
    unsigned int* bb = (unsigned int*)alloc((size_t)NE * 4);
    int*   rowp  = (int*)  alloc((size_t)(NN + 1) * 4);
    int*   bcnt  = (int*)  alloc((size_t)NBKT * 4);
    int*   bstart= (int*)  alloc((size_t)(NBKT + 1) * 4);
    int*   bcursor=(int*)  alloc((size_t)NBKT * 4);
    __half* xl2  = (__half*)alloc((size_t)NN * 16 * 2);
    float* xr2   = (float*)alloc((size_t)NN * 16 * 4);
    float* h2    = (float*)alloc((size_t)NN * 16 * 4);
    float* pooled= (float*)alloc((size_t)NB * 16 * 4);
    float* cnt   = (float*)alloc((size_t)NB * 4);

    hipMemsetAsync(bcnt, 0, (size_t)NBKT * 4, stream);
    k_gemm1<<<(NN + 31) / 32, 256, 0, stream>>>(x, wl1, bl1, wr1, br1, xl1, xr1);
    k_bhist<<<EBLK, 256, 0, stream>>>(ei, bcnt);
    k_bscan<<<1, 512, 0, stream>>>(bcnt, bstart, bcursor);
    k_bucket<<<EBLK, 256, 0, stream>>>(ei, bcursor, bb);
    k_bfinal<<<NBKT, 256, 0, stream>>>(bb, bstart, rowp, slist);
    k_conv1_agg<<<(NN * 64) / 256, 256, 0, stream>>>(xl1, xr1, att1, bias1, rowp, slist, h1);
    k_gemm2<<<(NN + 31) / 32, 256, 0, stream>>>(h1, wl2, bl2, wr2, br2, xl2, xr2);
    k_conv2_agg<<<(NN * 64) / 256, 256, 0, stream>>>(xl2, xr2, att2, bias2, rowp, slist, h2);
    k_pool<<<NB, 256, 0, stream>>>(h2, batch, pooled, cnt);
    k_mlp<<<1, 256, 0, stream>>>(pooled, cnt, wm1, bm1, wm2, bm2, wm3, bm3, out);
}